// Round 9
// baseline (354.973 us; speedup 1.0000x reference)
//
#include <hip/hip_runtime.h>

// Problem constants (from reference)
#define NNODES 50000
#define NEDGES 800000
#define INDIM  256
#define HIDC   64
#define HEADS  4
static constexpr int ETOT = NEDGES + NNODES;  // edges + self loops

typedef _Float16 half4 __attribute__((ext_vector_type(4)));
typedef _Float16 half8 __attribute__((ext_vector_type(8)));
typedef short    s16x8 __attribute__((ext_vector_type(8)));   // 8 bf16 (4 VGPR) MFMA frag
typedef short    s16x4 __attribute__((ext_vector_type(4)));
typedef float    f32x4 __attribute__((ext_vector_type(4)));   // MFMA accumulator

// bf16 helpers (RNE)
__device__ __forceinline__ unsigned short f2bf(float f) {
    unsigned u = __float_as_uint(f);
    u += 0x7fffu + ((u >> 16) & 1u);
    return (unsigned short)(u >> 16);
}
__device__ __forceinline__ float bf2f(unsigned short h) {
    return __uint_as_float(((unsigned)h) << 16);
}

// ---------------------------------------------------------------------------
// edge_index element-width detection (parallel): int64 => odd 32-bit words zero
__global__ void detect_k(const unsigned* __restrict__ ei32, int* __restrict__ flag) {
    __shared__ int any32;
    if (threadIdx.x == 0) any32 = 0;
    __syncthreads();
    if (ei32[1 + 2 * threadIdx.x] != 0u) any32 = 1;
    __syncthreads();
    if (threadIdx.x == 0) *flag = !any32;
}

__device__ __forceinline__ int load_idx(const void* ei, int is64, size_t pos) {
    return is64 ? (int)((const long long*)ei)[pos] : ((const int*)ei)[pos];
}

// ---------------------------------------------------------------------------
// CSR build: histogram of dst, two-level exclusive scan, scatter src ids
__global__ __launch_bounds__(256)
void hist_k(const void* __restrict__ ei, const int* __restrict__ flag,
            int* __restrict__ count) {
    int e = blockIdx.x * 256 + threadIdx.x;
    if (e >= ETOT) return;
    int is64 = *flag;
    int dst = (e < NEDGES) ? load_idx(ei, is64, (size_t)NEDGES + e) : (e - NEDGES);
    atomicAdd(&count[dst], 1);
}

// per-block exclusive scan of count -> rowptr (block-local), block sums -> bsum
__global__ __launch_bounds__(1024)
void scan1_k(const int* __restrict__ count, int* __restrict__ rowptr,
             int* __restrict__ bsum, int n) {
    __shared__ int wsum[16];
    const int tid = threadIdx.x;
    const int lane = tid & 63;
    const int w = tid >> 6;
    int i = blockIdx.x * 1024 + tid;
    int v = (i < n) ? count[i] : 0;
    int x = v;
    #pragma unroll
    for (int dd = 1; dd < 64; dd <<= 1) {
        int y = __shfl_up(x, dd);
        if (lane >= dd) x += y;
    }
    if (lane == 63) wsum[w] = x;
    __syncthreads();
    int woff = 0, total = 0;
    #pragma unroll
    for (int j = 0; j < 16; ++j) {
        if (j < w) woff += wsum[j];
        total += wsum[j];
    }
    if (i < n) rowptr[i] = woff + x - v;
    if (tid == 0) bsum[blockIdx.x] = total;
}

// scan of <=64 block sums (exclusive) in one wave
__global__ void scan2_k(int* __restrict__ bsum, int* __restrict__ bpre, int nb,
                        int* __restrict__ rowptr, int n) {
    int lane = threadIdx.x;
    int v = (lane < nb) ? bsum[lane] : 0;
    int x = v;
    #pragma unroll
    for (int dd = 1; dd < 64; dd <<= 1) {
        int y = __shfl_up(x, dd);
        if (lane >= dd) x += y;
    }
    if (lane < nb) bpre[lane] = x - v;
    if (lane == 63) rowptr[n] = x;  // grand total
}

__global__ __launch_bounds__(1024)
void scan3_k(int* __restrict__ rowptr, const int* __restrict__ bpre, int n) {
    int i = blockIdx.x * 1024 + threadIdx.x;
    if (i < n) rowptr[i] += bpre[blockIdx.x];
}

__global__ __launch_bounds__(256)
void scatter_k(const void* __restrict__ ei, const int* __restrict__ flag,
               const int* __restrict__ rowptr, int* __restrict__ fill,
               int* __restrict__ csr_src) {
    int e = blockIdx.x * 256 + threadIdx.x;
    if (e >= ETOT) return;
    int is64 = *flag;
    int src, dst;
    if (e < NEDGES) {
        src = load_idx(ei, is64, (size_t)e);
        dst = load_idx(ei, is64, (size_t)NEDGES + e);
    } else {
        src = e - NEDGES; dst = src;
    }
    int pos = rowptr[dst] + atomicAdd(&fill[dst], 1);
    csr_src[pos] = src;
}

// ---------------------------------------------------------------------------
// Weight pre-convert: W[K][N] fp32 -> Bt_hi/Bt_lo[N][K] bf16 (transposed)
__global__ __launch_bounds__(256)
void convw_k(const float* __restrict__ W, unsigned short* __restrict__ t_hi,
             unsigned short* __restrict__ t_lo, int K, int N) {
    int idx = blockIdx.x * 256 + threadIdx.x;
    if (idx >= K * N) return;
    int k = idx / N, n = idx % N;
    float w = W[idx];
    unsigned short hi = f2bf(w);
    unsigned short lo = f2bf(w - bf2f(hi));
    t_hi[(size_t)n * K + k] = hi;
    t_lo[(size_t)n * K + k] = lo;
}

// ---------------------------------------------------------------------------
// Split-bf16 MFMA GEMM: C[M,N] = A[M,K]@B[K,N]. BM=128, BK=32, 4 waves 2x2.
// SD=0: write C fp32 (+Ch row-major). SD=1: skip C; Ch HEAD-MAJOR
// ([col/64][row][col%64]) + direct store of s/d per-head dots (wave owns one
// head's 64 cols). SD=2: Ch row-major + atomicAdd s/d (S/D pre-zeroed).
template<int BN, int SD, bool HM>
__global__ __launch_bounds__(256)
void gemm_mfma_k(const float* __restrict__ A,
                 const unsigned short* __restrict__ Bt_hi,
                 const unsigned short* __restrict__ Bt_lo,
                 float* __restrict__ C, _Float16* __restrict__ Ch,
                 const float* __restrict__ asrc, const float* __restrict__ adst,
                 float* __restrict__ S, float* __restrict__ D,
                 int M, int N, int K) {
    constexpr int CB = BN / 32;          // 16-col frags per wave
    constexpr int BI = (BN * 4) / 256;   // B 16B-chunks per thread per half
    __shared__ unsigned short sAh[128][40], sAl[128][40];  // pad 40 (80B rows)
    __shared__ unsigned short sBh[BN][40], sBl[BN][40];
    const int tid = threadIdx.x;
    const int bm = blockIdx.y * 128;
    const int bn = blockIdx.x * BN;
    const int w = tid >> 6, lane = tid & 63;
    const int wr = w >> 1, wc = w & 1;
    const int lr = lane & 15, lk = lane >> 4;

    f32x4 acc[4][CB] = {};

    for (int k0 = 0; k0 < K; k0 += 32) {
        // global loads (A fp32 tile 128x32; B bf16 chunks)
        float4 av[4];
        #pragma unroll
        for (int i = 0; i < 4; ++i) {
            int idx = tid + 256 * i;
            int row = idx >> 3, c4 = idx & 7;
            int grow = bm + row; if (grow >= M) grow = M - 1;
            av[i] = *(const float4*)(A + (size_t)grow * K + k0 + c4 * 4);
        }
        s16x8 bhv[BI], blv[BI];
        #pragma unroll
        for (int i = 0; i < BI; ++i) {
            int idx = tid + 256 * i;
            int col = idx >> 2, ch = idx & 3;
            bhv[i] = *(const s16x8*)(Bt_hi + (size_t)(bn + col) * K + k0 + ch * 8);
            blv[i] = *(const s16x8*)(Bt_lo + (size_t)(bn + col) * K + k0 + ch * 8);
        }
        __syncthreads();
        #pragma unroll
        for (int i = 0; i < 4; ++i) {
            int idx = tid + 256 * i;
            int row = idx >> 3, c4 = idx & 7;
            float vs[4] = {av[i].x, av[i].y, av[i].z, av[i].w};
            unsigned short h[4], l[4];
            #pragma unroll
            for (int j = 0; j < 4; ++j) {
                h[j] = f2bf(vs[j]);
                l[j] = f2bf(vs[j] - bf2f(h[j]));
            }
            *(s16x4*)&sAh[row][c4 * 4] = (s16x4){(short)h[0], (short)h[1], (short)h[2], (short)h[3]};
            *(s16x4*)&sAl[row][c4 * 4] = (s16x4){(short)l[0], (short)l[1], (short)l[2], (short)l[3]};
        }
        #pragma unroll
        for (int i = 0; i < BI; ++i) {
            int idx = tid + 256 * i;
            int col = idx >> 2, ch = idx & 3;
            *(s16x8*)&sBh[col][ch * 8] = bhv[i];
            *(s16x8*)&sBl[col][ch * 8] = blv[i];
        }
        __syncthreads();
        // fragment loads + 3-term MFMA
        s16x8 afh[4], afl[4], bfh[CB], bfl[CB];
        #pragma unroll
        for (int rb = 0; rb < 4; ++rb) {
            int row = wr * 64 + rb * 16 + lr;
            afh[rb] = *(const s16x8*)&sAh[row][lk * 8];
            afl[rb] = *(const s16x8*)&sAl[row][lk * 8];
        }
        #pragma unroll
        for (int cb = 0; cb < CB; ++cb) {
            int col = wc * (BN / 2) + cb * 16 + lr;
            bfh[cb] = *(const s16x8*)&sBh[col][lk * 8];
            bfl[cb] = *(const s16x8*)&sBl[col][lk * 8];
        }
        #pragma unroll
        for (int rb = 0; rb < 4; ++rb)
            #pragma unroll
            for (int cb = 0; cb < CB; ++cb) {
                acc[rb][cb] = __builtin_amdgcn_mfma_f32_16x16x32_bf16(afh[rb], bfh[cb], acc[rb][cb], 0, 0, 0);
                acc[rb][cb] = __builtin_amdgcn_mfma_f32_16x16x32_bf16(afh[rb], bfl[cb], acc[rb][cb], 0, 0, 0);
                acc[rb][cb] = __builtin_amdgcn_mfma_f32_16x16x32_bf16(afl[rb], bfh[cb], acc[rb][cb], 0, 0, 0);
            }
    }
    // epilogue: C/D layout col=lane&15, row=(lane>>4)*4+r  [m89-verified]
    #pragma unroll
    for (int rb = 0; rb < 4; ++rb)
        #pragma unroll
        for (int cb = 0; cb < CB; ++cb)
            #pragma unroll
            for (int r = 0; r < 4; ++r) {
                int row = bm + wr * 64 + rb * 16 + lk * 4 + r;
                int col = bn + wc * (BN / 2) + cb * 16 + lr;
                if (row < M) {
                    float v = acc[rb][cb][r];
                    if constexpr (SD == 0) C[(size_t)row * N + col] = v;
                    if (Ch) {
                        size_t cidx = HM
                            ? ((size_t)(col >> 6) * M + row) * 64 + (col & 63)
                            : (size_t)row * N + col;
                        Ch[cidx] = (_Float16)v;
                    }
                }
            }
    // fused s/d epilogue
    if constexpr (SD != 0) {
        float af[CB], df[CB];
        #pragma unroll
        for (int cb = 0; cb < CB; ++cb) {
            int colg = bn + wc * (BN / 2) + cb * 16 + lr;
            af[cb] = asrc[colg];
            df[cb] = adst[colg];
        }
        #pragma unroll
        for (int rb = 0; rb < 4; ++rb)
            #pragma unroll
            for (int r = 0; r < 4; ++r) {
                float ps = 0.f, pd = 0.f;
                #pragma unroll
                for (int cb = 0; cb < CB; ++cb) {
                    ps += acc[rb][cb][r] * af[cb];
                    pd += acc[rb][cb][r] * df[cb];
                }
                #pragma unroll
                for (int m = 1; m < 16; m <<= 1) {
                    ps += __shfl_xor(ps, m);
                    pd += __shfl_xor(pd, m);
                }
                int row = bm + wr * 64 + rb * 16 + lk * 4 + r;
                if (lr == 0 && row < M) {
                    if constexpr (SD == 1) {
                        int head = (bn + wc * (BN / 2)) >> 6;
                        S[(size_t)row * (N >> 6) + head] = ps;
                        D[(size_t)row * (N >> 6) + head] = pd;
                    } else {
                        atomicAdd(&S[row], ps);
                        atomicAdd(&D[row], pd);
                    }
                }
            }
    }
}

// ---------------------------------------------------------------------------
// s[n,h] = sum_c h[n,h,c]*a_src[h,c]; d likewise. One wave per node. (fallback)
template<int H>
__global__ __launch_bounds__(256)
void sd_k(const float* __restrict__ hfeat, const float* __restrict__ a_src,
          const float* __restrict__ a_dst, float* __restrict__ s,
          float* __restrict__ d, int n) {
    const int lane = threadIdx.x & 63;
    const int node = blockIdx.x * 4 + (threadIdx.x >> 6);
    if (node >= n) return;
    const float* row = hfeat + (size_t)node * (H * 64);
    #pragma unroll
    for (int h = 0; h < H; ++h) {
        float f = row[h * 64 + lane];
        float vs = f * a_src[h * 64 + lane];
        float vd = f * a_dst[h * 64 + lane];
        #pragma unroll
        for (int m = 32; m; m >>= 1) {
            vs += __shfl_xor(vs, m);
            vd += __shfl_xor(vd, m);
        }
        if (lane == 0) { s[node * H + h] = vs; d[node * H + h] = vd; }
    }
}

// ---------------------------------------------------------------------------
__device__ __forceinline__ float leaky(float e) { return (e > 0.f) ? e : 0.2f * e; }

__device__ __forceinline__ float sel4(const float v[4], int idx) {
    float r = v[0];
    r = (idx == 1) ? v[1] : r;
    r = (idx == 2) ? v[2] : r;
    r = (idx == 3) ? v[3] : r;
    return r;
}

__device__ __forceinline__ void osm_upd(float& m, float& sm, float e) {
    float nm = fmaxf(m, e);
    sm = sm * __expf(m - nm) + __expf(e - nm);
    m = nm;
}

// ---------------------------------------------------------------------------
// Layer-1 attention pass 1: ex = exp(leaky(s[src]+d[dst])) -> ebuf head-major
// slices [h][edge]; wave-reduce denom -> invv[node][4]. One wave per node.
__global__ __launch_bounds__(256)
void pass1_k(const float* __restrict__ s, const float* __restrict__ d,
             const int* __restrict__ rowptr, const int* __restrict__ csr_src,
             float* __restrict__ ebuf, float* __restrict__ invv, int n) {
    const int lane = threadIdx.x & 63;
    const int node = blockIdx.x * 4 + (threadIdx.x >> 6);
    if (node >= n) return;
    const int beg = rowptr[node];
    const int end = rowptr[node + 1];
    float4 dh = ((const float4*)d)[node];
    float dn0 = 0.f, dn1 = 0.f, dn2 = 0.f, dn3 = 0.f;
    for (int i = beg + lane; i < end; i += 64) {
        int sidx = csr_src[i];
        float4 sv = ((const float4*)s)[sidx];
        float e0 = __expf(leaky(sv.x + dh.x));
        float e1 = __expf(leaky(sv.y + dh.y));
        float e2 = __expf(leaky(sv.z + dh.z));
        float e3 = __expf(leaky(sv.w + dh.w));
        ebuf[i] = e0;
        ebuf[(size_t)ETOT + i] = e1;
        ebuf[(size_t)2 * ETOT + i] = e2;
        ebuf[(size_t)3 * ETOT + i] = e3;
        dn0 += e0; dn1 += e1; dn2 += e2; dn3 += e3;
    }
    #pragma unroll
    for (int m = 32; m; m >>= 1) {
        dn0 += __shfl_xor(dn0, m); dn1 += __shfl_xor(dn1, m);
        dn2 += __shfl_xor(dn2, m); dn3 += __shfl_xor(dn3, m);
    }
    if (lane == 0) {
        float4 iv;
        iv.x = 1.f / (dn0 + 1e-16f); iv.y = 1.f / (dn1 + 1e-16f);
        iv.z = 1.f / (dn2 + 1e-16f); iv.w = 1.f / (dn3 + 1e-16f);
        ((float4*)invv)[node] = iv;
    }
}

// Layer-1 per-head gather pass: hh is the 6.4MB head slice [node][64] fp16
// (L2-friendly working set). 8 lanes/row (half8 = 16B), 16 edges in flight.
__global__ __launch_bounds__(256)
void agg3_k(const _Float16* __restrict__ hh, const float* __restrict__ exh,
            const float* __restrict__ invv, const float* __restrict__ bias,
            const int* __restrict__ rowptr, const int* __restrict__ csr_src,
            float* __restrict__ out, int head, int n) {
    const int lane = threadIdx.x & 63;
    const int node = blockIdx.x * 4 + (threadIdx.x >> 6);
    if (node >= n) return;
    const int beg = rowptr[node];
    const int end = rowptr[node + 1];
    const half8* H8 = (const half8*)hh;   // 8 half8 per row
    const int sub = lane >> 3;            // 0..7
    const int c8 = lane & 7;
    float acc[8] = {};
    int i = beg;
    for (; i + 15 < end; i += 16) {
        int e0 = i + sub, e1 = i + 8 + sub;
        int s0 = csr_src[e0], s1 = csr_src[e1];
        float x0 = exh[e0], x1 = exh[e1];
        half8 h0 = H8[(size_t)s0 * 8 + c8];
        half8 h1 = H8[(size_t)s1 * 8 + c8];
        #pragma unroll
        for (int j = 0; j < 8; ++j)
            acc[j] += x0 * (float)h0[j] + x1 * (float)h1[j];
    }
    for (; i < end; i += 8) {
        int e = i + sub;
        if (e < end) {
            int s0 = csr_src[e];
            float x = exh[e];
            half8 hh8 = H8[(size_t)s0 * 8 + c8];
            #pragma unroll
            for (int j = 0; j < 8; ++j) acc[j] += x * (float)hh8[j];
        }
    }
    #pragma unroll
    for (int m = 8; m <= 32; m <<= 1)
        #pragma unroll
        for (int j = 0; j < 8; ++j) acc[j] += __shfl_xor(acc[j], m);
    if (lane < 8) {
        float iv = invv[node * 4 + head];
        float4 b0 = *(const float4*)(bias + head * 64 + c8 * 8);
        float4 b1 = *(const float4*)(bias + head * 64 + c8 * 8 + 4);
        float4 o0, o1;
        o0.x = fmaxf(acc[0] * iv + b0.x, 0.f);
        o0.y = fmaxf(acc[1] * iv + b0.y, 0.f);
        o0.z = fmaxf(acc[2] * iv + b0.z, 0.f);
        o0.w = fmaxf(acc[3] * iv + b0.w, 0.f);
        o1.x = fmaxf(acc[4] * iv + b1.x, 0.f);
        o1.y = fmaxf(acc[5] * iv + b1.y, 0.f);
        o1.z = fmaxf(acc[6] * iv + b1.z, 0.f);
        o1.w = fmaxf(acc[7] * iv + b1.w, 0.f);
        *(float4*)(out + (size_t)node * 256 + head * 64 + c8 * 8) = o0;
        *(float4*)(out + (size_t)node * 256 + head * 64 + c8 * 8 + 4) = o1;
    }
}

// ---------------------------------------------------------------------------
// GAT attention + aggregation (layer 2 / fallback), one wave per dst node.
template<int H, bool EB>
__global__ __launch_bounds__(256)
void agg_k(const float* __restrict__ hfeat, const _Float16* __restrict__ hhalf,
           const float* __restrict__ s, const float* __restrict__ d,
           const float* __restrict__ bias, const int* __restrict__ rowptr,
           const int* __restrict__ csr_src, float* __restrict__ ebuf,
           float* __restrict__ out, int n) {
    const int lane = threadIdx.x & 63;
    const int node = blockIdx.x * 4 + (threadIdx.x >> 6);
    if (node >= n) return;
    const int beg = rowptr[node];
    const int end = rowptr[node + 1];
    float dh[H], dn[H], inv[H];
    #pragma unroll
    for (int h = 0; h < H; ++h) {
        dh[h] = d[node * H + h];
        dn[h] = 0.f;
    }

    if constexpr (EB) {
        for (int i = beg + lane; i < end; i += 64) {
            int sidx = csr_src[i];
            if constexpr (H == 4) {
                float4 sv = *(const float4*)(s + (size_t)sidx * 4);
                float4 ex;
                ex.x = __expf(leaky(sv.x + dh[0]));
                ex.y = __expf(leaky(sv.y + dh[1]));
                ex.z = __expf(leaky(sv.z + dh[2]));
                ex.w = __expf(leaky(sv.w + dh[3]));
                *(float4*)(ebuf + (size_t)i * 4) = ex;
                dn[0] += ex.x; dn[1] += ex.y; dn[2] += ex.z; dn[3] += ex.w;
            } else {
                float ex = __expf(leaky(s[sidx] + dh[0]));
                ebuf[i] = ex;
                dn[0] += ex;
            }
        }
        #pragma unroll
        for (int h = 0; h < H; ++h) {
            #pragma unroll
            for (int m = 32; m; m >>= 1) dn[h] += __shfl_xor(dn[h], m);
            inv[h] = 1.f / (dn[h] + 1e-16f);
        }

        if constexpr (H == 4) {
            const half8* H8 = (const half8*)hhalf;   // 32 half8 per row
            const int sub = lane >> 5;
            const int c8 = lane & 31;
            const int head = c8 >> 3;
            const float invh = sel4(inv, head);
            float acc[8] = {};
            int i = beg;
            for (; i + 7 < end; i += 8) {
                int e0 = i + sub, e1 = i + 2 + sub, e2 = i + 4 + sub, e3 = i + 6 + sub;
                int s0 = csr_src[e0], s1 = csr_src[e1];
                int s2 = csr_src[e2], s3 = csr_src[e3];
                float x0 = ebuf[(size_t)e0 * 4 + head];
                float x1 = ebuf[(size_t)e1 * 4 + head];
                float x2 = ebuf[(size_t)e2 * 4 + head];
                float x3 = ebuf[(size_t)e3 * 4 + head];
                half8 h0 = H8[(size_t)s0 * 32 + c8];
                half8 h1 = H8[(size_t)s1 * 32 + c8];
                half8 h2 = H8[(size_t)s2 * 32 + c8];
                half8 h3 = H8[(size_t)s3 * 32 + c8];
                #pragma unroll
                for (int j = 0; j < 8; ++j)
                    acc[j] += x0 * (float)h0[j] + x1 * (float)h1[j]
                            + x2 * (float)h2[j] + x3 * (float)h3[j];
            }
            for (; i < end; i += 2) {
                int e = i + sub;
                if (e < end) {
                    int s0 = csr_src[e];
                    float x = ebuf[(size_t)e * 4 + head];
                    half8 hh = H8[(size_t)s0 * 32 + c8];
                    #pragma unroll
                    for (int j = 0; j < 8; ++j) acc[j] += x * (float)hh[j];
                }
            }
            #pragma unroll
            for (int j = 0; j < 8; ++j) acc[j] += __shfl_xor(acc[j], 32);
            if (lane < 32) {
                float4 b0 = *(const float4*)(bias + c8 * 8);
                float4 b1 = *(const float4*)(bias + c8 * 8 + 4);
                float4 o0, o1;
                o0.x = fmaxf(acc[0] * invh + b0.x, 0.f);
                o0.y = fmaxf(acc[1] * invh + b0.y, 0.f);
                o0.z = fmaxf(acc[2] * invh + b0.z, 0.f);
                o0.w = fmaxf(acc[3] * invh + b0.w, 0.f);
                o1.x = fmaxf(acc[4] * invh + b1.x, 0.f);
                o1.y = fmaxf(acc[5] * invh + b1.y, 0.f);
                o1.z = fmaxf(acc[6] * invh + b1.z, 0.f);
                o1.w = fmaxf(acc[7] * invh + b1.w, 0.f);
                *(float4*)(out + (size_t)node * 256 + c8 * 8) = o0;
                *(float4*)(out + (size_t)node * 256 + c8 * 8 + 4) = o1;
            }
        } else {
            const half8* H8 = (const half8*)hhalf;   // 8 half8 per row
            const int sub = lane >> 3;
            const int c8 = lane & 7;
            float acc[8] = {};
            int i = beg;
            for (; i + 15 < end; i += 16) {
                int e0 = i + sub, e1 = i + 8 + sub;
                int s0 = csr_src[e0], s1 = csr_src[e1];
                float x0 = ebuf[e0], x1 = ebuf[e1];
                half8 h0 = H8[(size_t)s0 * 8 + c8];
                half8 h1 = H8[(size_t)s1 * 8 + c8];
                #pragma unroll
                for (int j = 0; j < 8; ++j)
                    acc[j] += x0 * (float)h0[j] + x1 * (float)h1[j];
            }
            for (; i < end; i += 8) {
                int e = i + sub;
                if (e < end) {
                    int s0 = csr_src[e];
                    float x = ebuf[e];
                    half8 hh = H8[(size_t)s0 * 8 + c8];
                    #pragma unroll
                    for (int j = 0; j < 8; ++j) acc[j] += x * (float)hh[j];
                }
            }
            #pragma unroll
            for (int m = 8; m <= 32; m <<= 1)
                #pragma unroll
                for (int j = 0; j < 8; ++j) acc[j] += __shfl_xor(acc[j], m);
            if (lane < 8) {
                float4 b0 = *(const float4*)(bias + c8 * 8);
                float4 b1 = *(const float4*)(bias + c8 * 8 + 4);
                float4 o0, o1;
                o0.x = fmaxf(acc[0] * inv[0] + b0.x, 0.f);
                o0.y = fmaxf(acc[1] * inv[0] + b0.y, 0.f);
                o0.z = fmaxf(acc[2] * inv[0] + b0.z, 0.f);
                o0.w = fmaxf(acc[3] * inv[0] + b0.w, 0.f);
                o1.x = fmaxf(acc[4] * inv[0] + b1.x, 0.f);
                o1.y = fmaxf(acc[5] * inv[0] + b1.y, 0.f);
                o1.z = fmaxf(acc[6] * inv[0] + b1.z, 0.f);
                o1.w = fmaxf(acc[7] * inv[0] + b1.w, 0.f);
                *(float4*)(out + (size_t)node * 64 + c8 * 8) = o0;
                *(float4*)(out + (size_t)node * 64 + c8 * 8 + 4) = o1;
            }
        }
    } else {
        // fallback (no ebuf): online softmax + serial recompute, fp32 h
        float mx[H], sm[H];
        #pragma unroll
        for (int h = 0; h < H; ++h) { mx[h] = -3.0e38f; sm[h] = 0.f; }
        for (int i = beg + lane; i < end; i += 64) {
            int sidx = csr_src[i];
            if constexpr (H == 4) {
                float4 sv = *(const float4*)(s + (size_t)sidx * 4);
                osm_upd(mx[0], sm[0], leaky(sv.x + dh[0]));
                osm_upd(mx[1], sm[1], leaky(sv.y + dh[1]));
                osm_upd(mx[2], sm[2], leaky(sv.z + dh[2]));
                osm_upd(mx[3], sm[3], leaky(sv.w + dh[3]));
            } else {
                osm_upd(mx[0], sm[0], leaky(s[sidx] + dh[0]));
            }
        }
        #pragma unroll
        for (int h = 0; h < H; ++h) {
            #pragma unroll
            for (int dd = 32; dd; dd >>= 1) {
                float om = __shfl_xor(mx[h], dd);
                float os = __shfl_xor(sm[h], dd);
                float nm = fmaxf(mx[h], om);
                sm[h] = sm[h] * __expf(mx[h] - nm) + os * __expf(om - nm);
                mx[h] = nm;
            }
            inv[h] = 1.f / (sm[h] + 1e-16f);
        }
        if constexpr (H == 4) {
            const int head = lane >> 4;
            const float invh = sel4(inv, head);
            const float mxh = sel4(mx, head);
            const float dhh = sel4(dh, head);
            const float4* H4 = (const float4*)hfeat;
            float4 acc = {0.f, 0.f, 0.f, 0.f};
            for (int i = beg; i < end; ++i) {
                int s0 = csr_src[i];
                float al0 = __expf(leaky(s[(size_t)s0 * 4 + head] + dhh) - mxh) * invh;
                float4 h0 = H4[(size_t)s0 * 64 + lane];
                acc.x += al0 * h0.x; acc.y += al0 * h0.y;
                acc.z += al0 * h0.z; acc.w += al0 * h0.w;
            }
            float4 bv = ((const float4*)bias)[lane];
            float4 o;
            o.x = fmaxf(acc.x + bv.x, 0.f); o.y = fmaxf(acc.y + bv.y, 0.f);
            o.z = fmaxf(acc.z + bv.z, 0.f); o.w = fmaxf(acc.w + bv.w, 0.f);
            ((float4*)out)[(size_t)node * 64 + lane] = o;
        } else {
            float acc = 0.f;
            for (int i = beg; i < end; ++i) {
                int s0 = csr_src[i];
                float a0 = __expf(leaky(s[s0] + dh[0]) - mx[0]) * inv[0];
                acc += a0 * hfeat[(size_t)s0 * 64 + lane];
            }
            float v = acc + bias[lane];
            out[(size_t)node * 64 + lane] = fmaxf(v, 0.f);
        }
    }
}

// ---------------------------------------------------------------------------
// Fused FF: out = softmax(relu(in@Wf1+bf1)@Wf2+bf2). Grid-stride; weights in
// LDS once per block. xrow/yrow are wave-private (no cross-wave barrier).
__global__ __launch_bounds__(256)
void ff_k(const float* __restrict__ in, const float* __restrict__ Wf1,
          const float* __restrict__ bf1, const float* __restrict__ Wf2,
          const float* __restrict__ bf2, float* __restrict__ out, int n) {
    __shared__ float w1[64 * 64];
    __shared__ float w2[64 * 64];
    __shared__ float xrow[4][64];
    __shared__ float yrow[4][64];
    const int tid = threadIdx.x;
    for (int i = tid; i < 64 * 64; i += 256) { w1[i] = Wf1[i]; w2[i] = Wf2[i]; }
    __syncthreads();
    const int wv = tid >> 6;
    const int lane = tid & 63;
    const float B1 = bf1[lane], B2 = bf2[lane];
    const int nblk = (n + 3) / 4;
    for (int nb = blockIdx.x; nb < nblk; nb += gridDim.x) {
        int node = nb * 4 + wv;
        int nd = node < n ? node : (n - 1);
        float x = in[(size_t)nd * 64 + lane];
        xrow[wv][lane] = x;
        float y = B1;
        #pragma unroll 8
        for (int k = 0; k < 64; ++k) y += xrow[wv][k] * w1[k * 64 + lane];
        y = fmaxf(y, 0.f);
        yrow[wv][lane] = y;
        float z = B2;
        #pragma unroll 8
        for (int k = 0; k < 64; ++k) z += yrow[wv][k] * w2[k * 64 + lane];
        float m = z;
        #pragma unroll
        for (int dd = 32; dd; dd >>= 1) m = fmaxf(m, __shfl_xor(m, dd));
        float ex = __expf(z - m);
        float sum = ex;
        #pragma unroll
        for (int dd = 32; dd; dd >>= 1) sum += __shfl_xor(sum, dd);
        if (node < n) out[(size_t)node * 64 + lane] = ex / sum;
    }
}

// ---------------------------------------------------------------------------
extern "C" void kernel_launch(void* const* d_in, const int* in_sizes, int n_in,
                              void* d_out, int out_size, void* d_ws, size_t ws_size,
                              hipStream_t stream) {
    const float* x      = (const float*)d_in[0];
    const void*  ei     = d_in[1];
    const float* W1     = (const float*)d_in[2];
    const float* a_src1 = (const float*)d_in[3];
    const float* a_dst1 = (const float*)d_in[4];
    const float* b1     = (const float*)d_in[5];
    const float* W2     = (const float*)d_in[6];
    const float* a_src2 = (const float*)d_in[7];
    const float* a_dst2 = (const float*)d_in[8];
    const float* b2     = (const float*)d_in[9];
    const float* Wf1    = (const float*)d_in[10];
    const float* bf1    = (const float*)d_in[11];
    const float* Wf2    = (const float*)d_in[12];
    const float* bf2    = (const float*)d_in[13];
    float* outp = (float*)d_out;

    // workspace carve-up (256B aligned)
    char* ws = (char*)d_ws;
    size_t off = 0;
    auto take = [&](size_t bytes) -> char* {
        char* p = ws + off;
        off += (bytes + 255) & ~(size_t)255;
        return p;
    };
    int*   flag   = (int*)take(4);
    int*   count  = (int*)take((size_t)NNODES * 4);
    int*   fill   = (int*)take((size_t)NNODES * 4);
    int*   rowptr = (int*)take((size_t)(NNODES + 1) * 4);
    int*   bsum   = (int*)take(64 * 4);
    int*   bpre   = (int*)take(64 * 4);
    int*   csr    = (int*)take((size_t)ETOT * 4);
    unsigned short* w1t_hi = (unsigned short*)take((size_t)256 * 256 * 2);
    unsigned short* w1t_lo = (unsigned short*)take((size_t)256 * 256 * 2);
    unsigned short* w2t_hi = (unsigned short*)take((size_t)64 * 256 * 2);
    unsigned short* w2t_lo = (unsigned short*)take((size_t)64 * 256 * 2);
    float* h1     = (float*)take((size_t)NNODES * 256 * 4);   // fallback only
    float* agg1   = (float*)take((size_t)NNODES * 256 * 4);
    float* s1     = (float*)take((size_t)NNODES * HEADS * 4);
    float* d1     = (float*)take((size_t)NNODES * HEADS * 4);
    float* invv   = (float*)take((size_t)NNODES * HEADS * 4);
    float* ebuf   = (float*)take((size_t)ETOT * HEADS * 4);
    _Float16* h1h = (_Float16*)take((size_t)NNODES * 256 * 2);
    const bool eb_ok = (off <= ws_size);
    // reuse dead buffers for layer 2
    float*    h2   = h1;
    float*    s2   = s1;
    float*    d2   = d1;
    float*    agg2 = agg1;
    _Float16* h2h  = h1h;

    // CSR build (shared by both GAT layers)
    detect_k<<<1, 128, 0, stream>>>((const unsigned*)ei, flag);
    hipMemsetAsync(count, 0, (size_t)NNODES * 4, stream);
    hipMemsetAsync(fill, 0, (size_t)NNODES * 4, stream);
    const int eblocks = (ETOT + 255) / 256;
    hist_k<<<eblocks, 256, 0, stream>>>(ei, flag, count);
    const int sblocks = (NNODES + 1023) / 1024;  // 49
    scan1_k<<<sblocks, 1024, 0, stream>>>(count, rowptr, bsum, NNODES);
    scan2_k<<<1, 64, 0, stream>>>(bsum, bpre, sblocks, rowptr, NNODES);
    scan3_k<<<sblocks, 1024, 0, stream>>>(rowptr, bpre, NNODES);
    scatter_k<<<eblocks, 256, 0, stream>>>(ei, flag, rowptr, fill, csr);

    // Weight pre-convert (tiny)
    convw_k<<<(256 * 256) / 256, 256, 0, stream>>>(W1, w1t_hi, w1t_lo, 256, 256);
    convw_k<<<(256 * 64) / 256, 256, 0, stream>>>(W2, w2t_hi, w2t_lo, 256, 64);

    const int nodeblocks = NNODES / 4;  // 12500
    const int mblocks = (NNODES + 127) / 128;  // 391
    const dim3 gg1(2, mblocks);   // N=256, BN=128
    const dim3 gg2(1, mblocks);   // N=64,  BN=64

    if (eb_ok) {
        // Layer 1: GEMM + fused s/d; h1h stored HEAD-MAJOR ([h][node][64])
        gemm_mfma_k<128, 1, true><<<gg1, 256, 0, stream>>>(x, w1t_hi, w1t_lo,
            nullptr, h1h, a_src1, a_dst1, s1, d1, NNODES, 256, 256);
        // attention pass 1 (ex -> head-major ebuf slices; inv per node/head)
        pass1_k<<<nodeblocks, 256, 0, stream>>>(s1, d1, rowptr, csr, ebuf, invv, NNODES);
        // per-head gather passes (6.4MB working set each)
        for (int h = 0; h < HEADS; ++h)
            agg3_k<<<nodeblocks, 256, 0, stream>>>(
                h1h + (size_t)h * NNODES * 64, ebuf + (size_t)h * ETOT,
                invv, b1, rowptr, csr, agg1, h, NNODES);

        // Layer 2: GEMM + fused s/d (atomic; zero s2/d2 first)
        hipMemsetAsync(s2, 0, (size_t)NNODES * 4, stream);
        hipMemsetAsync(d2, 0, (size_t)NNODES * 4, stream);
        gemm_mfma_k<64, 2, false><<<gg2, 256, 0, stream>>>(agg1, w2t_hi, w2t_lo,
            nullptr, h2h, a_src2, a_dst2, s2, d2, NNODES, 64, 256);
        agg_k<1, true><<<nodeblocks, 256, 0, stream>>>(h2, h2h, s2, d2, b2,
            rowptr, csr, ebuf, agg2, NNODES);
    } else {
        gemm_mfma_k<128, 0, false><<<gg1, 256, 0, stream>>>(x, w1t_hi, w1t_lo,
            h1, nullptr, nullptr, nullptr, nullptr, nullptr, NNODES, 256, 256);
        sd_k<HEADS><<<nodeblocks, 256, 0, stream>>>(h1, a_src1, a_dst1, s1, d1, NNODES);
        agg_k<HEADS, false><<<nodeblocks, 256, 0, stream>>>(h1, h1h, s1, d1, b1,
            rowptr, csr, ebuf, agg1, NNODES);
        gemm_mfma_k<64, 0, false><<<gg2, 256, 0, stream>>>(agg1, w2t_hi, w2t_lo,
            h2, nullptr, nullptr, nullptr, nullptr, nullptr, NNODES, 64, 256);
        sd_k<1><<<nodeblocks, 256, 0, stream>>>(h2, a_src2, a_dst2, s2, d2, NNODES);
        agg_k<1, false><<<nodeblocks, 256, 0, stream>>>(h2, h2h, s2, d2, b2,
            rowptr, csr, ebuf, agg2, NNODES);
    }

    // FF + softmax
    ff_k<<<1024, 256, 0, stream>>>(agg2, Wf1, bf1, Wf2, bf2, outp, NNODES);
}

// Round 10
// 291.698 us; speedup vs baseline: 1.2169x; 1.2169x over previous
//
#include <hip/hip_runtime.h>

// Problem constants (from reference)
#define NNODES 50000
#define NEDGES 800000
#define INDIM  256
#define HIDC   64
#define HEADS  4
static constexpr int ETOT = NEDGES + NNODES;  // edges + self loops

typedef _Float16 half4 __attribute__((ext_vector_type(4)));
typedef _Float16 half8 __attribute__((ext_vector_type(8)));
typedef short    s16x8 __attribute__((ext_vector_type(8)));   // 8 bf16 (4 VGPR) MFMA frag
typedef short    s16x4 __attribute__((ext_vector_type(4)));
typedef float    f32x4 __attribute__((ext_vector_type(4)));   // MFMA accumulator

// bf16 helpers (RNE)
__device__ __forceinline__ unsigned short f2bf(float f) {
    unsigned u = __float_as_uint(f);
    u += 0x7fffu + ((u >> 16) & 1u);
    return (unsigned short)(u >> 16);
}
__device__ __forceinline__ float bf2f(unsigned short h) {
    return __uint_as_float(((unsigned)h) << 16);
}

// ---------------------------------------------------------------------------
// edge_index element-width detection (parallel): int64 => odd 32-bit words zero
__global__ void detect_k(const unsigned* __restrict__ ei32, int* __restrict__ flag) {
    __shared__ int any32;
    if (threadIdx.x == 0) any32 = 0;
    __syncthreads();
    if (ei32[1 + 2 * threadIdx.x] != 0u) any32 = 1;
    __syncthreads();
    if (threadIdx.x == 0) *flag = !any32;
}

__device__ __forceinline__ int load_idx(const void* ei, int is64, size_t pos) {
    return is64 ? (int)((const long long*)ei)[pos] : ((const int*)ei)[pos];
}

// ---------------------------------------------------------------------------
// CSR build: histogram of dst, two-level exclusive scan, scatter src ids
__global__ __launch_bounds__(256)
void hist_k(const void* __restrict__ ei, const int* __restrict__ flag,
            int* __restrict__ count) {
    int e = blockIdx.x * 256 + threadIdx.x;
    if (e >= ETOT) return;
    int is64 = *flag;
    int dst = (e < NEDGES) ? load_idx(ei, is64, (size_t)NEDGES + e) : (e - NEDGES);
    atomicAdd(&count[dst], 1);
}

// per-block exclusive scan of count -> rowptr (block-local), block sums -> bsum
__global__ __launch_bounds__(1024)
void scan1_k(const int* __restrict__ count, int* __restrict__ rowptr,
             int* __restrict__ bsum, int n) {
    __shared__ int wsum[16];
    const int tid = threadIdx.x;
    const int lane = tid & 63;
    const int w = tid >> 6;
    int i = blockIdx.x * 1024 + tid;
    int v = (i < n) ? count[i] : 0;
    int x = v;
    #pragma unroll
    for (int dd = 1; dd < 64; dd <<= 1) {
        int y = __shfl_up(x, dd);
        if (lane >= dd) x += y;
    }
    if (lane == 63) wsum[w] = x;
    __syncthreads();
    int woff = 0, total = 0;
    #pragma unroll
    for (int j = 0; j < 16; ++j) {
        if (j < w) woff += wsum[j];
        total += wsum[j];
    }
    if (i < n) rowptr[i] = woff + x - v;
    if (tid == 0) bsum[blockIdx.x] = total;
}

// scan of <=64 block sums (exclusive) in one wave
__global__ void scan2_k(int* __restrict__ bsum, int* __restrict__ bpre, int nb,
                        int* __restrict__ rowptr, int n) {
    int lane = threadIdx.x;
    int v = (lane < nb) ? bsum[lane] : 0;
    int x = v;
    #pragma unroll
    for (int dd = 1; dd < 64; dd <<= 1) {
        int y = __shfl_up(x, dd);
        if (lane >= dd) x += y;
    }
    if (lane < nb) bpre[lane] = x - v;
    if (lane == 63) rowptr[n] = x;  // grand total
}

__global__ __launch_bounds__(1024)
void scan3_k(int* __restrict__ rowptr, const int* __restrict__ bpre, int n) {
    int i = blockIdx.x * 1024 + threadIdx.x;
    if (i < n) rowptr[i] += bpre[blockIdx.x];
}

__global__ __launch_bounds__(256)
void scatter_k(const void* __restrict__ ei, const int* __restrict__ flag,
               const int* __restrict__ rowptr, int* __restrict__ fill,
               int* __restrict__ csr_src) {
    int e = blockIdx.x * 256 + threadIdx.x;
    if (e >= ETOT) return;
    int is64 = *flag;
    int src, dst;
    if (e < NEDGES) {
        src = load_idx(ei, is64, (size_t)e);
        dst = load_idx(ei, is64, (size_t)NEDGES + e);
    } else {
        src = e - NEDGES; dst = src;
    }
    int pos = rowptr[dst] + atomicAdd(&fill[dst], 1);
    csr_src[pos] = src;
}

// ---------------------------------------------------------------------------
// Weight pre-convert: W[K][N] fp32 -> Bt_hi/Bt_lo[N][K] bf16 (transposed)
__global__ __launch_bounds__(256)
void convw_k(const float* __restrict__ W, unsigned short* __restrict__ t_hi,
             unsigned short* __restrict__ t_lo, int K, int N) {
    int idx = blockIdx.x * 256 + threadIdx.x;
    if (idx >= K * N) return;
    int k = idx / N, n = idx % N;
    float w = W[idx];
    unsigned short hi = f2bf(w);
    unsigned short lo = f2bf(w - bf2f(hi));
    t_hi[(size_t)n * K + k] = hi;
    t_lo[(size_t)n * K + k] = lo;
}

// ---------------------------------------------------------------------------
// Split-bf16 MFMA GEMM: C[M,N] = A[M,K]@B[K,N]. BM=128, BK=32, 4 waves 2x2.
// SD=0: write C fp32 (+Ch). SD=1: skip C; Ch + direct store of s/d per-head
// dots (wave owns one head's 64 cols). SD=2: Ch + atomicAdd s/d (pre-zeroed).
template<int BN, int SD>
__global__ __launch_bounds__(256)
void gemm_mfma_k(const float* __restrict__ A,
                 const unsigned short* __restrict__ Bt_hi,
                 const unsigned short* __restrict__ Bt_lo,
                 float* __restrict__ C, _Float16* __restrict__ Ch,
                 const float* __restrict__ asrc, const float* __restrict__ adst,
                 float* __restrict__ S, float* __restrict__ D,
                 int M, int N, int K) {
    constexpr int CB = BN / 32;          // 16-col frags per wave
    constexpr int BI = (BN * 4) / 256;   // B 16B-chunks per thread per half
    __shared__ unsigned short sAh[128][40], sAl[128][40];  // pad 40 (80B rows)
    __shared__ unsigned short sBh[BN][40], sBl[BN][40];
    const int tid = threadIdx.x;
    const int bm = blockIdx.y * 128;
    const int bn = blockIdx.x * BN;
    const int w = tid >> 6, lane = tid & 63;
    const int wr = w >> 1, wc = w & 1;
    const int lr = lane & 15, lk = lane >> 4;

    f32x4 acc[4][CB] = {};

    for (int k0 = 0; k0 < K; k0 += 32) {
        float4 av[4];
        #pragma unroll
        for (int i = 0; i < 4; ++i) {
            int idx = tid + 256 * i;
            int row = idx >> 3, c4 = idx & 7;
            int grow = bm + row; if (grow >= M) grow = M - 1;
            av[i] = *(const float4*)(A + (size_t)grow * K + k0 + c4 * 4);
        }
        s16x8 bhv[BI], blv[BI];
        #pragma unroll
        for (int i = 0; i < BI; ++i) {
            int idx = tid + 256 * i;
            int col = idx >> 2, ch = idx & 3;
            bhv[i] = *(const s16x8*)(Bt_hi + (size_t)(bn + col) * K + k0 + ch * 8);
            blv[i] = *(const s16x8*)(Bt_lo + (size_t)(bn + col) * K + k0 + ch * 8);
        }
        __syncthreads();
        #pragma unroll
        for (int i = 0; i < 4; ++i) {
            int idx = tid + 256 * i;
            int row = idx >> 3, c4 = idx & 7;
            float vs[4] = {av[i].x, av[i].y, av[i].z, av[i].w};
            unsigned short h[4], l[4];
            #pragma unroll
            for (int j = 0; j < 4; ++j) {
                h[j] = f2bf(vs[j]);
                l[j] = f2bf(vs[j] - bf2f(h[j]));
            }
            *(s16x4*)&sAh[row][c4 * 4] = (s16x4){(short)h[0], (short)h[1], (short)h[2], (short)h[3]};
            *(s16x4*)&sAl[row][c4 * 4] = (s16x4){(short)l[0], (short)l[1], (short)l[2], (short)l[3]};
        }
        #pragma unroll
        for (int i = 0; i < BI; ++i) {
            int idx = tid + 256 * i;
            int col = idx >> 2, ch = idx & 3;
            *(s16x8*)&sBh[col][ch * 8] = bhv[i];
            *(s16x8*)&sBl[col][ch * 8] = blv[i];
        }
        __syncthreads();
        s16x8 afh[4], afl[4], bfh[CB], bfl[CB];
        #pragma unroll
        for (int rb = 0; rb < 4; ++rb) {
            int row = wr * 64 + rb * 16 + lr;
            afh[rb] = *(const s16x8*)&sAh[row][lk * 8];
            afl[rb] = *(const s16x8*)&sAl[row][lk * 8];
        }
        #pragma unroll
        for (int cb = 0; cb < CB; ++cb) {
            int col = wc * (BN / 2) + cb * 16 + lr;
            bfh[cb] = *(const s16x8*)&sBh[col][lk * 8];
            bfl[cb] = *(const s16x8*)&sBl[col][lk * 8];
        }
        #pragma unroll
        for (int rb = 0; rb < 4; ++rb)
            #pragma unroll
            for (int cb = 0; cb < CB; ++cb) {
                acc[rb][cb] = __builtin_amdgcn_mfma_f32_16x16x32_bf16(afh[rb], bfh[cb], acc[rb][cb], 0, 0, 0);
                acc[rb][cb] = __builtin_amdgcn_mfma_f32_16x16x32_bf16(afh[rb], bfl[cb], acc[rb][cb], 0, 0, 0);
                acc[rb][cb] = __builtin_amdgcn_mfma_f32_16x16x32_bf16(afl[rb], bfh[cb], acc[rb][cb], 0, 0, 0);
            }
    }
    // epilogue: C/D layout col=lane&15, row=(lane>>4)*4+r  [m89-verified]
    #pragma unroll
    for (int rb = 0; rb < 4; ++rb)
        #pragma unroll
        for (int cb = 0; cb < CB; ++cb)
            #pragma unroll
            for (int r = 0; r < 4; ++r) {
                int row = bm + wr * 64 + rb * 16 + lk * 4 + r;
                int col = bn + wc * (BN / 2) + cb * 16 + lr;
                if (row < M) {
                    float v = acc[rb][cb][r];
                    if constexpr (SD == 0) C[(size_t)row * N + col] = v;
                    if (Ch) Ch[(size_t)row * N + col] = (_Float16)v;
                }
            }
    // fused s/d epilogue
    if constexpr (SD != 0) {
        float af[CB], df[CB];
        #pragma unroll
        for (int cb = 0; cb < CB; ++cb) {
            int colg = bn + wc * (BN / 2) + cb * 16 + lr;
            af[cb] = asrc[colg];
            df[cb] = adst[colg];
        }
        #pragma unroll
        for (int rb = 0; rb < 4; ++rb)
            #pragma unroll
            for (int r = 0; r < 4; ++r) {
                float ps = 0.f, pd = 0.f;
                #pragma unroll
                for (int cb = 0; cb < CB; ++cb) {
                    ps += acc[rb][cb][r] * af[cb];
                    pd += acc[rb][cb][r] * df[cb];
                }
                #pragma unroll
                for (int m = 1; m < 16; m <<= 1) {
                    ps += __shfl_xor(ps, m);
                    pd += __shfl_xor(pd, m);
                }
                int row = bm + wr * 64 + rb * 16 + lk * 4 + r;
                if (lr == 0 && row < M) {
                    if constexpr (SD == 1) {
                        int head = (bn + wc * (BN / 2)) >> 6;
                        S[(size_t)row * (N >> 6) + head] = ps;
                        D[(size_t)row * (N >> 6) + head] = pd;
                    } else {
                        atomicAdd(&S[row], ps);
                        atomicAdd(&D[row], pd);
                    }
                }
            }
    }
}

// ---------------------------------------------------------------------------
// s/d fallback kernel
template<int H>
__global__ __launch_bounds__(256)
void sd_k(const float* __restrict__ hfeat, const float* __restrict__ a_src,
          const float* __restrict__ a_dst, float* __restrict__ s,
          float* __restrict__ d, int n) {
    const int lane = threadIdx.x & 63;
    const int node = blockIdx.x * 4 + (threadIdx.x >> 6);
    if (node >= n) return;
    const float* row = hfeat + (size_t)node * (H * 64);
    #pragma unroll
    for (int h = 0; h < H; ++h) {
        float f = row[h * 64 + lane];
        float vs = f * a_src[h * 64 + lane];
        float vd = f * a_dst[h * 64 + lane];
        #pragma unroll
        for (int m = 32; m; m >>= 1) {
            vs += __shfl_xor(vs, m);
            vd += __shfl_xor(vd, m);
        }
        if (lane == 0) { s[node * H + h] = vs; d[node * H + h] = vd; }
    }
}

// ---------------------------------------------------------------------------
__device__ __forceinline__ float leaky(float e) { return (e > 0.f) ? e : 0.2f * e; }

__device__ __forceinline__ float sel4(const float v[4], int idx) {
    float r = v[0];
    r = (idx == 1) ? v[1] : r;
    r = (idx == 2) ? v[2] : r;
    r = (idx == 3) ? v[3] : r;
    return r;
}

__device__ __forceinline__ void osm_upd(float& m, float& sm, float e) {
    float nm = fmaxf(m, e);
    sm = sm * __expf(m - nm) + __expf(e - nm);
    m = nm;
}

// GAT attention + aggregation, one wave per dst node (round-8 tuned form).
template<int H, bool EB>
__global__ __launch_bounds__(256)
void agg_k(const float* __restrict__ hfeat, const _Float16* __restrict__ hhalf,
           const float* __restrict__ s, const float* __restrict__ d,
           const float* __restrict__ bias, const int* __restrict__ rowptr,
           const int* __restrict__ csr_src, float* __restrict__ ebuf,
           float* __restrict__ out, int n) {
    const int lane = threadIdx.x & 63;
    const int node = blockIdx.x * 4 + (threadIdx.x >> 6);
    if (node >= n) return;
    const int beg = rowptr[node];
    const int end = rowptr[node + 1];
    float dh[H], dn[H], inv[H];
    #pragma unroll
    for (int h = 0; h < H; ++h) {
        dh[h] = d[node * H + h];
        dn[h] = 0.f;
    }

    if constexpr (EB) {
        for (int i = beg + lane; i < end; i += 64) {
            int sidx = csr_src[i];
            if constexpr (H == 4) {
                float4 sv = *(const float4*)(s + (size_t)sidx * 4);
                float4 ex;
                ex.x = __expf(leaky(sv.x + dh[0]));
                ex.y = __expf(leaky(sv.y + dh[1]));
                ex.z = __expf(leaky(sv.z + dh[2]));
                ex.w = __expf(leaky(sv.w + dh[3]));
                *(float4*)(ebuf + (size_t)i * 4) = ex;
                dn[0] += ex.x; dn[1] += ex.y; dn[2] += ex.z; dn[3] += ex.w;
            } else {
                float ex = __expf(leaky(s[sidx] + dh[0]));
                ebuf[i] = ex;
                dn[0] += ex;
            }
        }
        #pragma unroll
        for (int h = 0; h < H; ++h) {
            #pragma unroll
            for (int m = 32; m; m >>= 1) dn[h] += __shfl_xor(dn[h], m);
            inv[h] = 1.f / (dn[h] + 1e-16f);
        }

        if constexpr (H == 4) {
            // 32 lanes per row (half8 = 16B/lane), 2 edges/instr, 8 in flight
            const half8* H8 = (const half8*)hhalf;   // 32 half8 per row
            const int sub = lane >> 5;
            const int c8 = lane & 31;
            const int head = c8 >> 3;
            const float invh = sel4(inv, head);
            float acc[8] = {};
            int i = beg;
            for (; i + 7 < end; i += 8) {
                int e0 = i + sub, e1 = i + 2 + sub, e2 = i + 4 + sub, e3 = i + 6 + sub;
                int s0 = csr_src[e0], s1 = csr_src[e1];
                int s2 = csr_src[e2], s3 = csr_src[e3];
                float x0 = ebuf[(size_t)e0 * 4 + head];
                float x1 = ebuf[(size_t)e1 * 4 + head];
                float x2 = ebuf[(size_t)e2 * 4 + head];
                float x3 = ebuf[(size_t)e3 * 4 + head];
                half8 h0 = H8[(size_t)s0 * 32 + c8];
                half8 h1 = H8[(size_t)s1 * 32 + c8];
                half8 h2 = H8[(size_t)s2 * 32 + c8];
                half8 h3 = H8[(size_t)s3 * 32 + c8];
                #pragma unroll
                for (int j = 0; j < 8; ++j)
                    acc[j] += x0 * (float)h0[j] + x1 * (float)h1[j]
                            + x2 * (float)h2[j] + x3 * (float)h3[j];
            }
            for (; i < end; i += 2) {
                int e = i + sub;
                if (e < end) {
                    int s0 = csr_src[e];
                    float x = ebuf[(size_t)e * 4 + head];
                    half8 hh = H8[(size_t)s0 * 32 + c8];
                    #pragma unroll
                    for (int j = 0; j < 8; ++j) acc[j] += x * (float)hh[j];
                }
            }
            #pragma unroll
            for (int j = 0; j < 8; ++j) acc[j] += __shfl_xor(acc[j], 32);
            if (lane < 32) {
                float4 b0 = *(const float4*)(bias + c8 * 8);
                float4 b1 = *(const float4*)(bias + c8 * 8 + 4);
                float4 o0, o1;
                o0.x = fmaxf(acc[0] * invh + b0.x, 0.f);
                o0.y = fmaxf(acc[1] * invh + b0.y, 0.f);
                o0.z = fmaxf(acc[2] * invh + b0.z, 0.f);
                o0.w = fmaxf(acc[3] * invh + b0.w, 0.f);
                o1.x = fmaxf(acc[4] * invh + b1.x, 0.f);
                o1.y = fmaxf(acc[5] * invh + b1.y, 0.f);
                o1.z = fmaxf(acc[6] * invh + b1.z, 0.f);
                o1.w = fmaxf(acc[7] * invh + b1.w, 0.f);
                *(float4*)(out + (size_t)node * 256 + c8 * 8) = o0;
                *(float4*)(out + (size_t)node * 256 + c8 * 8 + 4) = o1;
            }
        } else {
            // 8 lanes per row (half8), 8 edges/instr, 16 in flight
            const half8* H8 = (const half8*)hhalf;   // 8 half8 per row
            const int sub = lane >> 3;
            const int c8 = lane & 7;
            float acc[8] = {};
            int i = beg;
            for (; i + 15 < end; i += 16) {
                int e0 = i + sub, e1 = i + 8 + sub;
                int s0 = csr_src[e0], s1 = csr_src[e1];
                float x0 = ebuf[e0], x1 = ebuf[e1];
                half8 h0 = H8[(size_t)s0 * 8 + c8];
                half8 h1 = H8[(size_t)s1 * 8 + c8];
                #pragma unroll
                for (int j = 0; j < 8; ++j)
                    acc[j] += x0 * (float)h0[j] + x1 * (float)h1[j];
            }
            for (; i < end; i += 8) {
                int e = i + sub;
                if (e < end) {
                    int s0 = csr_src[e];
                    float x = ebuf[e];
                    half8 hh = H8[(size_t)s0 * 8 + c8];
                    #pragma unroll
                    for (int j = 0; j < 8; ++j) acc[j] += x * (float)hh[j];
                }
            }
            #pragma unroll
            for (int m = 8; m <= 32; m <<= 1)
                #pragma unroll
                for (int j = 0; j < 8; ++j) acc[j] += __shfl_xor(acc[j], m);
            if (lane < 8) {
                float4 b0 = *(const float4*)(bias + c8 * 8);
                float4 b1 = *(const float4*)(bias + c8 * 8 + 4);
                float4 o0, o1;
                o0.x = fmaxf(acc[0] * inv[0] + b0.x, 0.f);
                o0.y = fmaxf(acc[1] * inv[0] + b0.y, 0.f);
                o0.z = fmaxf(acc[2] * inv[0] + b0.z, 0.f);
                o0.w = fmaxf(acc[3] * inv[0] + b0.w, 0.f);
                o1.x = fmaxf(acc[4] * inv[0] + b1.x, 0.f);
                o1.y = fmaxf(acc[5] * inv[0] + b1.y, 0.f);
                o1.z = fmaxf(acc[6] * inv[0] + b1.z, 0.f);
                o1.w = fmaxf(acc[7] * inv[0] + b1.w, 0.f);
                *(float4*)(out + (size_t)node * 64 + c8 * 8) = o0;
                *(float4*)(out + (size_t)node * 64 + c8 * 8 + 4) = o1;
            }
        }
    } else {
        // fallback (no ebuf): online softmax + serial recompute, fp32 h
        float mx[H], sm[H];
        #pragma unroll
        for (int h = 0; h < H; ++h) { mx[h] = -3.0e38f; sm[h] = 0.f; }
        for (int i = beg + lane; i < end; i += 64) {
            int sidx = csr_src[i];
            if constexpr (H == 4) {
                float4 sv = *(const float4*)(s + (size_t)sidx * 4);
                osm_upd(mx[0], sm[0], leaky(sv.x + dh[0]));
                osm_upd(mx[1], sm[1], leaky(sv.y + dh[1]));
                osm_upd(mx[2], sm[2], leaky(sv.z + dh[2]));
                osm_upd(mx[3], sm[3], leaky(sv.w + dh[3]));
            } else {
                osm_upd(mx[0], sm[0], leaky(s[sidx] + dh[0]));
            }
        }
        #pragma unroll
        for (int h = 0; h < H; ++h) {
            #pragma unroll
            for (int dd = 32; dd; dd >>= 1) {
                float om = __shfl_xor(mx[h], dd);
                float os = __shfl_xor(sm[h], dd);
                float nm = fmaxf(mx[h], om);
                sm[h] = sm[h] * __expf(mx[h] - nm) + os * __expf(om - nm);
                mx[h] = nm;
            }
            inv[h] = 1.f / (sm[h] + 1e-16f);
        }
        if constexpr (H == 4) {
            const int head = lane >> 4;
            const float invh = sel4(inv, head);
            const float mxh = sel4(mx, head);
            const float dhh = sel4(dh, head);
            const float4* H4 = (const float4*)hfeat;
            float4 acc = {0.f, 0.f, 0.f, 0.f};
            for (int i = beg; i < end; ++i) {
                int s0 = csr_src[i];
                float al0 = __expf(leaky(s[(size_t)s0 * 4 + head] + dhh) - mxh) * invh;
                float4 h0 = H4[(size_t)s0 * 64 + lane];
                acc.x += al0 * h0.x; acc.y += al0 * h0.y;
                acc.z += al0 * h0.z; acc.w += al0 * h0.w;
            }
            float4 bv = ((const float4*)bias)[lane];
            float4 o;
            o.x = fmaxf(acc.x + bv.x, 0.f); o.y = fmaxf(acc.y + bv.y, 0.f);
            o.z = fmaxf(acc.z + bv.z, 0.f); o.w = fmaxf(acc.w + bv.w, 0.f);
            ((float4*)out)[(size_t)node * 64 + lane] = o;
        } else {
            float acc = 0.f;
            for (int i = beg; i < end; ++i) {
                int s0 = csr_src[i];
                float a0 = __expf(leaky(s[s0] + dh[0]) - mx[0]) * inv[0];
                acc += a0 * hfeat[(size_t)s0 * 64 + lane];
            }
            float v = acc + bias[lane];
            out[(size_t)node * 64 + lane] = fmaxf(v, 0.f);
        }
    }
}

// ---------------------------------------------------------------------------
// MFMA fused FF: out = softmax(relu(in@Wf1+bf1)@Wf2+bf2). 64-row blocks,
// 4 waves each owning 16 rows x all 64 cols (rows wave-local => in-wave
// softmax). Weights pre-converted split-bf16 transposed [n][k]. LDS 61KB.
__global__ __launch_bounds__(256)
void ffm_k(const float* __restrict__ in,
           const unsigned short* __restrict__ w1h, const unsigned short* __restrict__ w1l,
           const float* __restrict__ bf1,
           const unsigned short* __restrict__ w2h, const unsigned short* __restrict__ w2l,
           const float* __restrict__ bf2, float* __restrict__ out, int M) {
    __shared__ unsigned short sAh[64][80], sAl[64][80];    // K chunks: [k/32]*40+(k%32)
    __shared__ unsigned short sW1h[64][80], sW1l[64][80];  // [n][kchunked]
    __shared__ unsigned short sW2h[64][80], sW2l[64][80];
    const int tid = threadIdx.x;
    const int bm = blockIdx.x * 64;
    const int w = tid >> 6, lane = tid & 63;
    const int lr = lane & 15, lk = lane >> 4;

    // stage weights (coalesced 16B chunks)
    for (int c = tid; c < 512; c += 256) {
        int n = c >> 3, k8 = c & 7;
        int dcol = (k8 >> 2) * 40 + (k8 & 3) * 8;
        *(s16x8*)&sW1h[n][dcol] = *(const s16x8*)(w1h + n * 64 + k8 * 8);
        *(s16x8*)&sW1l[n][dcol] = *(const s16x8*)(w1l + n * 64 + k8 * 8);
        *(s16x8*)&sW2h[n][dcol] = *(const s16x8*)(w2h + n * 64 + k8 * 8);
        *(s16x8*)&sW2l[n][dcol] = *(const s16x8*)(w2l + n * 64 + k8 * 8);
    }
    // stage A tile (64 rows x 16 float4), split-bf16 convert
    #pragma unroll
    for (int i = 0; i < 4; ++i) {
        int c = tid + 256 * i;              // 0..1023
        int row = c >> 4, c4 = c & 15;
        int grow = bm + row; if (grow >= M) grow = M - 1;
        float4 av = *(const float4*)(in + (size_t)grow * 64 + c4 * 4);
        float vs[4] = {av.x, av.y, av.z, av.w};
        unsigned short h[4], l[4];
        #pragma unroll
        for (int j = 0; j < 4; ++j) {
            h[j] = f2bf(vs[j]);
            l[j] = f2bf(vs[j] - bf2f(h[j]));
        }
        int dcol = (c4 >> 3) * 40 + (c4 & 7) * 4;
        *(s16x4*)&sAh[row][dcol] = (s16x4){(short)h[0], (short)h[1], (short)h[2], (short)h[3]};
        *(s16x4*)&sAl[row][dcol] = (s16x4){(short)l[0], (short)l[1], (short)l[2], (short)l[3]};
    }
    __syncthreads();
    // layer 1: 3-term split-bf16 MFMA, wave w owns rows w*16..w*16+15
    f32x4 a1[4] = {};
    #pragma unroll
    for (int ks = 0; ks < 2; ++ks) {
        int koff = ks * 40 + lk * 8;
        s16x8 ah = *(const s16x8*)&sAh[w * 16 + lr][koff];
        s16x8 al = *(const s16x8*)&sAl[w * 16 + lr][koff];
        #pragma unroll
        for (int cb = 0; cb < 4; ++cb) {
            s16x8 bh = *(const s16x8*)&sW1h[cb * 16 + lr][koff];
            s16x8 bl = *(const s16x8*)&sW1l[cb * 16 + lr][koff];
            a1[cb] = __builtin_amdgcn_mfma_f32_16x16x32_bf16(ah, bh, a1[cb], 0, 0, 0);
            a1[cb] = __builtin_amdgcn_mfma_f32_16x16x32_bf16(ah, bl, a1[cb], 0, 0, 0);
            a1[cb] = __builtin_amdgcn_mfma_f32_16x16x32_bf16(al, bh, a1[cb], 0, 0, 0);
        }
    }
    __syncthreads();  // A reads complete before overwrite with y
    // epilogue 1: y = relu(acc + bf1[col]) -> split bf16 back into sA
    #pragma unroll
    for (int cb = 0; cb < 4; ++cb) {
        int col = cb * 16 + lr;
        float b = bf1[col];
        int dcol = (col >> 5) * 40 + (col & 31);
        #pragma unroll
        for (int r = 0; r < 4; ++r) {
            int row = w * 16 + lk * 4 + r;
            float y = fmaxf(a1[cb][r] + b, 0.f);
            unsigned short hh = f2bf(y);
            sAh[row][dcol] = hh;
            sAl[row][dcol] = f2bf(y - bf2f(hh));
        }
    }
    __syncthreads();
    // layer 2
    f32x4 a2[4] = {};
    #pragma unroll
    for (int ks = 0; ks < 2; ++ks) {
        int koff = ks * 40 + lk * 8;
        s16x8 ah = *(const s16x8*)&sAh[w * 16 + lr][koff];
        s16x8 al = *(const s16x8*)&sAl[w * 16 + lr][koff];
        #pragma unroll
        for (int cb = 0; cb < 4; ++cb) {
            s16x8 bh = *(const s16x8*)&sW2h[cb * 16 + lr][koff];
            s16x8 bl = *(const s16x8*)&sW2l[cb * 16 + lr][koff];
            a2[cb] = __builtin_amdgcn_mfma_f32_16x16x32_bf16(ah, bh, a2[cb], 0, 0, 0);
            a2[cb] = __builtin_amdgcn_mfma_f32_16x16x32_bf16(ah, bl, a2[cb], 0, 0, 0);
            a2[cb] = __builtin_amdgcn_mfma_f32_16x16x32_bf16(al, bh, a2[cb], 0, 0, 0);
        }
    }
    // softmax epilogue: rows are wave-local; reduce across lr (16 lanes) + cb
    float zb[4];
    #pragma unroll
    for (int cb = 0; cb < 4; ++cb) zb[cb] = bf2[cb * 16 + lr];
    #pragma unroll
    for (int r = 0; r < 4; ++r) {
        int row = bm + w * 16 + lk * 4 + r;
        float z0 = a2[0][r] + zb[0], z1 = a2[1][r] + zb[1];
        float z2 = a2[2][r] + zb[2], z3 = a2[3][r] + zb[3];
        float m = fmaxf(fmaxf(z0, z1), fmaxf(z2, z3));
        #pragma unroll
        for (int dd = 1; dd < 16; dd <<= 1) m = fmaxf(m, __shfl_xor(m, dd));
        float e0 = __expf(z0 - m), e1 = __expf(z1 - m);
        float e2 = __expf(z2 - m), e3 = __expf(z3 - m);
        float sum = e0 + e1 + e2 + e3;
        #pragma unroll
        for (int dd = 1; dd < 16; dd <<= 1) sum += __shfl_xor(sum, dd);
        float is = 1.f / sum;
        if (row < M) {
            out[(size_t)row * 64 + 0 + lr]  = e0 * is;
            out[(size_t)row * 64 + 16 + lr] = e1 * is;
            out[(size_t)row * 64 + 32 + lr] = e2 * is;
            out[(size_t)row * 64 + 48 + lr] = e3 * is;
        }
    }
}

// ---------------------------------------------------------------------------
// Fallback FF (vector): out = softmax(relu(in@Wf1+bf1)@Wf2+bf2).
__global__ __launch_bounds__(256)
void ff_k(const float* __restrict__ in, const float* __restrict__ Wf1,
          const float* __restrict__ bf1, const float* __restrict__ Wf2,
          const float* __restrict__ bf2, float* __restrict__ out, int n) {
    __shared__ float w1[64 * 64];
    __shared__ float w2[64 * 64];
    __shared__ float xrow[4][64];
    __shared__ float yrow[4][64];
    const int tid = threadIdx.x;
    for (int i = tid; i < 64 * 64; i += 256) { w1[i] = Wf1[i]; w2[i] = Wf2[i]; }
    __syncthreads();
    const int wv = tid >> 6;
    const int lane = tid & 63;
    const float B1 = bf1[lane], B2 = bf2[lane];
    const int nblk = (n + 3) / 4;
    for (int nb = blockIdx.x; nb < nblk; nb += gridDim.x) {
        int node = nb * 4 + wv;
        int nd = node < n ? node : (n - 1);
        float x = in[(size_t)nd * 64 + lane];
        xrow[wv][lane] = x;
        float y = B1;
        #pragma unroll 8
        for (int k = 0; k < 64; ++k) y += xrow[wv][k] * w1[k * 64 + lane];
        y = fmaxf(y, 0.f);
        yrow[wv][lane] = y;
        float z = B2;
        #pragma unroll 8
        for (int k = 0; k < 64; ++k) z += yrow[wv][k] * w2[k * 64 + lane];
        float m = z;
        #pragma unroll
        for (int dd = 32; dd; dd >>= 1) m = fmaxf(m, __shfl_xor(m, dd));
        float ex = __expf(z - m);
        float sum = ex;
        #pragma unroll
        for (int dd = 32; dd; dd >>= 1) sum += __shfl_xor(sum, dd);
        if (node < n) out[(size_t)node * 64 + lane] = ex / sum;
    }
}

// ---------------------------------------------------------------------------
extern "C" void kernel_launch(void* const* d_in, const int* in_sizes, int n_in,
                              void* d_out, int out_size, void* d_ws, size_t ws_size,
                              hipStream_t stream) {
    const float* x      = (const float*)d_in[0];
    const void*  ei     = d_in[1];
    const float* W1     = (const float*)d_in[2];
    const float* a_src1 = (const float*)d_in[3];
    const float* a_dst1 = (const float*)d_in[4];
    const float* b1     = (const float*)d_in[5];
    const float* W2     = (const float*)d_in[6];
    const float* a_src2 = (const float*)d_in[7];
    const float* a_dst2 = (const float*)d_in[8];
    const float* b2     = (const float*)d_in[9];
    const float* Wf1    = (const float*)d_in[10];
    const float* bf1    = (const float*)d_in[11];
    const float* Wf2    = (const float*)d_in[12];
    const float* bf2    = (const float*)d_in[13];
    float* outp = (float*)d_out;

    // workspace carve-up (256B aligned)
    char* ws = (char*)d_ws;
    size_t off = 0;
    auto take = [&](size_t bytes) -> char* {
        char* p = ws + off;
        off += (bytes + 255) & ~(size_t)255;
        return p;
    };
    int*   flag   = (int*)take(4);
    int*   count  = (int*)take((size_t)NNODES * 4);
    int*   fill   = (int*)take((size_t)NNODES * 4);
    int*   rowptr = (int*)take((size_t)(NNODES + 1) * 4);
    int*   bsum   = (int*)take(64 * 4);
    int*   bpre   = (int*)take(64 * 4);
    int*   csr    = (int*)take((size_t)ETOT * 4);
    unsigned short* w1t_hi = (unsigned short*)take((size_t)256 * 256 * 2);
    unsigned short* w1t_lo = (unsigned short*)take((size_t)256 * 256 * 2);
    unsigned short* w2t_hi = (unsigned short*)take((size_t)64 * 256 * 2);
    unsigned short* w2t_lo = (unsigned short*)take((size_t)64 * 256 * 2);
    unsigned short* wf1t_hi = (unsigned short*)take((size_t)64 * 64 * 2);
    unsigned short* wf1t_lo = (unsigned short*)take((size_t)64 * 64 * 2);
    unsigned short* wf2t_hi = (unsigned short*)take((size_t)64 * 64 * 2);
    unsigned short* wf2t_lo = (unsigned short*)take((size_t)64 * 64 * 2);
    float* h1     = (float*)take((size_t)NNODES * 256 * 4);   // fallback only
    float* agg1   = (float*)take((size_t)NNODES * 256 * 4);
    float* s1     = (float*)take((size_t)NNODES * HEADS * 4);
    float* d1     = (float*)take((size_t)NNODES * HEADS * 4);
    float* ebuf   = (float*)take((size_t)ETOT * HEADS * 4);
    _Float16* h1h = (_Float16*)take((size_t)NNODES * 256 * 2);
    const bool eb_ok = (off <= ws_size);
    // reuse dead buffers for layer 2
    float*    h2   = h1;
    float*    s2   = s1;
    float*    d2   = d1;
    float*    agg2 = agg1;
    _Float16* h2h  = h1h;

    // CSR build (shared by both GAT layers)
    detect_k<<<1, 128, 0, stream>>>((const unsigned*)ei, flag);
    hipMemsetAsync(count, 0, (size_t)NNODES * 4, stream);
    hipMemsetAsync(fill, 0, (size_t)NNODES * 4, stream);
    const int eblocks = (ETOT + 255) / 256;
    hist_k<<<eblocks, 256, 0, stream>>>(ei, flag, count);
    const int sblocks = (NNODES + 1023) / 1024;  // 49
    scan1_k<<<sblocks, 1024, 0, stream>>>(count, rowptr, bsum, NNODES);
    scan2_k<<<1, 64, 0, stream>>>(bsum, bpre, sblocks, rowptr, NNODES);
    scan3_k<<<sblocks, 1024, 0, stream>>>(rowptr, bpre, NNODES);
    scatter_k<<<eblocks, 256, 0, stream>>>(ei, flag, rowptr, fill, csr);

    // Weight pre-convert (tiny)
    convw_k<<<(256 * 256) / 256, 256, 0, stream>>>(W1, w1t_hi, w1t_lo, 256, 256);
    convw_k<<<(256 * 64) / 256, 256, 0, stream>>>(W2, w2t_hi, w2t_lo, 256, 64);
    convw_k<<<(64 * 64) / 256, 256, 0, stream>>>(Wf1, wf1t_hi, wf1t_lo, 64, 64);
    convw_k<<<(64 * 64) / 256, 256, 0, stream>>>(Wf2, wf2t_hi, wf2t_lo, 64, 64);

    const int nodeblocks = NNODES / 4;  // 12500
    const int mblocks = (NNODES + 127) / 128;  // 391
    const dim3 gg1(2, mblocks);   // N=256, BN=128
    const dim3 gg2(1, mblocks);   // N=64,  BN=64

    if (eb_ok) {
        // Layer 1: GEMM + fused s/d (direct store; each wave owns one head)
        gemm_mfma_k<128, 1><<<gg1, 256, 0, stream>>>(x, w1t_hi, w1t_lo,
            nullptr, h1h, a_src1, a_dst1, s1, d1, NNODES, 256, 256);
        agg_k<HEADS, true><<<nodeblocks, 256, 0, stream>>>(h1, h1h, s1, d1, b1,
            rowptr, csr, ebuf, agg1, NNODES);

        // Layer 2: GEMM + fused s/d (atomic; zero s2/d2 first)
        hipMemsetAsync(s2, 0, (size_t)NNODES * 4, stream);
        hipMemsetAsync(d2, 0, (size_t)NNODES * 4, stream);
        gemm_mfma_k<64, 2><<<gg2, 256, 0, stream>>>(agg1, w2t_hi, w2t_lo,
            nullptr, h2h, a_src2, a_dst2, s2, d2, NNODES, 64, 256);
        agg_k<1, true><<<nodeblocks, 256, 0, stream>>>(h2, h2h, s2, d2, b2,
            rowptr, csr, ebuf, agg2, NNODES);

        // FF + softmax via MFMA
        ffm_k<<<(NNODES + 63) / 64, 256, 0, stream>>>(agg2, wf1t_hi, wf1t_lo,
            bf1, wf2t_hi, wf2t_lo, bf2, outp, NNODES);
    } else {
        gemm_mfma_k<128, 0><<<gg1, 256, 0, stream>>>(x, w1t_hi, w1t_lo,
            h1, nullptr, nullptr, nullptr, nullptr, nullptr, NNODES, 256, 256);
        sd_k<HEADS><<<nodeblocks, 256, 0, stream>>>(h1, a_src1, a_dst1, s1, d1, NNODES);
        agg_k<HEADS, false><<<nodeblocks, 256, 0, stream>>>(h1, h1h, s1, d1, b1,
            rowptr, csr, ebuf, agg1, NNODES);
        gemm_mfma_k<64, 0><<<gg2, 256, 0, stream>>>(agg1, w2t_hi, w2t_lo,
            h2, nullptr, nullptr, nullptr, nullptr, nullptr, NNODES, 64, 256);
        sd_k<1><<<nodeblocks, 256, 0, stream>>>(h2, a_src2, a_dst2, s2, d2, NNODES);
        agg_k<1, false><<<nodeblocks, 256, 0, stream>>>(h2, h2h, s2, d2, b2,
            rowptr, csr, ebuf, agg2, NNODES);
        ff_k<<<1024, 256, 0, stream>>>(agg2, Wf1, bf1, Wf2, bf2, outp, NNODES);
    }
}

// Round 11
// 280.263 us; speedup vs baseline: 1.2666x; 1.0408x over previous
//
#include <hip/hip_runtime.h>

// Problem constants (from reference)
#define NNODES 50000
#define NEDGES 800000
#define INDIM  256
#define HIDC   64
#define HEADS  4
static constexpr int ETOT = NEDGES + NNODES;  // edges + self loops

typedef _Float16 half8 __attribute__((ext_vector_type(8)));
typedef short    s16x8 __attribute__((ext_vector_type(8)));   // 8 bf16 (4 VGPR) MFMA frag
typedef short    s16x4 __attribute__((ext_vector_type(4)));
typedef float    f32x4 __attribute__((ext_vector_type(4)));   // MFMA accumulator

// bf16 helpers (RNE)
__device__ __forceinline__ unsigned short f2bf(float f) {
    unsigned u = __float_as_uint(f);
    u += 0x7fffu + ((u >> 16) & 1u);
    return (unsigned short)(u >> 16);
}
__device__ __forceinline__ float bf2f(unsigned short h) {
    return __uint_as_float(((unsigned)h) << 16);
}

// ---------------------------------------------------------------------------
// inline edge-width detection: int64 => odd 32-bit words of first 32 pairs all
// zero (false-positive prob ~ (2e-5)^32 ~ 0). Uniform scalar loads, L2-hot.
__device__ __forceinline__ int is_int64(const unsigned* __restrict__ ei32) {
    int r = 1;
    #pragma unroll
    for (int i = 1; i < 64; i += 2) r &= (ei32[i] == 0u);
    return r;
}

__device__ __forceinline__ int load_idx(const void* ei, int is64, size_t pos) {
    return is64 ? (int)((const long long*)ei)[pos] : ((const int*)ei)[pos];
}

// ---------------------------------------------------------------------------
// CSR build: histogram of dst, two-level exclusive scan, scatter src ids
__global__ __launch_bounds__(256)
void hist_k(const void* __restrict__ ei, int* __restrict__ count) {
    int e = blockIdx.x * 256 + threadIdx.x;
    if (e >= ETOT) return;
    int is64 = is_int64((const unsigned*)ei);
    int dst = (e < NEDGES) ? load_idx(ei, is64, (size_t)NEDGES + e) : (e - NEDGES);
    atomicAdd(&count[dst], 1);
}

__global__ __launch_bounds__(1024)
void scan1_k(const int* __restrict__ count, int* __restrict__ rowptr,
             int* __restrict__ bsum, int n) {
    __shared__ int wsum[16];
    const int tid = threadIdx.x;
    const int lane = tid & 63;
    const int w = tid >> 6;
    int i = blockIdx.x * 1024 + tid;
    int v = (i < n) ? count[i] : 0;
    int x = v;
    #pragma unroll
    for (int dd = 1; dd < 64; dd <<= 1) {
        int y = __shfl_up(x, dd);
        if (lane >= dd) x += y;
    }
    if (lane == 63) wsum[w] = x;
    __syncthreads();
    int woff = 0, total = 0;
    #pragma unroll
    for (int j = 0; j < 16; ++j) {
        if (j < w) woff += wsum[j];
        total += wsum[j];
    }
    if (i < n) rowptr[i] = woff + x - v;
    if (tid == 0) bsum[blockIdx.x] = total;
}

__global__ void scan2_k(int* __restrict__ bsum, int* __restrict__ bpre, int nb,
                        int* __restrict__ rowptr, int n) {
    int lane = threadIdx.x;
    int v = (lane < nb) ? bsum[lane] : 0;
    int x = v;
    #pragma unroll
    for (int dd = 1; dd < 64; dd <<= 1) {
        int y = __shfl_up(x, dd);
        if (lane >= dd) x += y;
    }
    if (lane < nb) bpre[lane] = x - v;
    if (lane == 63) rowptr[n] = x;  // grand total
}

__global__ __launch_bounds__(1024)
void scan3_k(int* __restrict__ rowptr, const int* __restrict__ bpre, int n) {
    int i = blockIdx.x * 1024 + threadIdx.x;
    if (i < n) rowptr[i] += bpre[blockIdx.x];
}

__global__ __launch_bounds__(256)
void scatter_k(const void* __restrict__ ei, const int* __restrict__ rowptr,
               int* __restrict__ fill, int* __restrict__ csr_src) {
    int e = blockIdx.x * 256 + threadIdx.x;
    if (e >= ETOT) return;
    int is64 = is_int64((const unsigned*)ei);
    int src, dst;
    if (e < NEDGES) {
        src = load_idx(ei, is64, (size_t)e);
        dst = load_idx(ei, is64, (size_t)NEDGES + e);
    } else {
        src = e - NEDGES; dst = src;
    }
    int pos = rowptr[dst] + atomicAdd(&fill[dst], 1);
    csr_src[pos] = src;
}

// ---------------------------------------------------------------------------
// All-weights pre-convert in one launch: W[K][N] fp32 -> hi/lo bf16 [N][K]
__global__ __launch_bounds__(256)
void convall_k(const float* __restrict__ W1, const float* __restrict__ W2,
               const float* __restrict__ Wf1, const float* __restrict__ Wf2,
               unsigned short* __restrict__ w1h, unsigned short* __restrict__ w1l,
               unsigned short* __restrict__ w2h, unsigned short* __restrict__ w2l,
               unsigned short* __restrict__ f1h, unsigned short* __restrict__ f1l,
               unsigned short* __restrict__ f2h, unsigned short* __restrict__ f2l) {
    int idx = blockIdx.x * 256 + threadIdx.x;
    const float* W; unsigned short *th, *tl; int K, N;
    if (idx < 65536)       { W = W1;  th = w1h; tl = w1l; K = 256; N = 256; }
    else if (idx < 81920)  { idx -= 65536; W = W2;  th = w2h; tl = w2l; K = 256; N = 64; }
    else if (idx < 86016)  { idx -= 81920; W = Wf1; th = f1h; tl = f1l; K = 64;  N = 64; }
    else if (idx < 90112)  { idx -= 86016; W = Wf2; th = f2h; tl = f2l; K = 64;  N = 64; }
    else return;
    int k = idx / N, n = idx % N;
    float w = W[(size_t)k * N + n];
    unsigned short hi = f2bf(w);
    unsigned short lo = f2bf(w - bf2f(hi));
    th[(size_t)n * K + k] = hi;
    tl[(size_t)n * K + k] = lo;
}

// ---------------------------------------------------------------------------
// Split-bf16 MFMA GEMM: BM=128, BK=32, 4 waves 2x2. Writes fp16 Ch + fused
// s/d dots. SD=1: direct store (wave owns one head's 64 cols). SD=2:
// atomicAdd (wave owns half a head; S/D pre-zeroed; exactly 2 contributors
// per row => bitwise-deterministic fp add).
template<int BN, int SD>
__global__ __launch_bounds__(256)
void gemm_mfma_k(const float* __restrict__ A,
                 const unsigned short* __restrict__ Bt_hi,
                 const unsigned short* __restrict__ Bt_lo,
                 _Float16* __restrict__ Ch,
                 const float* __restrict__ asrc, const float* __restrict__ adst,
                 float* __restrict__ S, float* __restrict__ D,
                 int M, int N, int K) {
    constexpr int CB = BN / 32;          // 16-col frags per wave
    constexpr int BI = (BN * 4) / 256;   // B 16B-chunks per thread per half
    __shared__ unsigned short sAh[128][40], sAl[128][40];  // pad 40 (80B rows)
    __shared__ unsigned short sBh[BN][40], sBl[BN][40];
    const int tid = threadIdx.x;
    const int bm = blockIdx.y * 128;
    const int bn = blockIdx.x * BN;
    const int w = tid >> 6, lane = tid & 63;
    const int wr = w >> 1, wc = w & 1;
    const int lr = lane & 15, lk = lane >> 4;

    f32x4 acc[4][CB] = {};

    for (int k0 = 0; k0 < K; k0 += 32) {
        float4 av[4];
        #pragma unroll
        for (int i = 0; i < 4; ++i) {
            int idx = tid + 256 * i;
            int row = idx >> 3, c4 = idx & 7;
            int grow = bm + row; if (grow >= M) grow = M - 1;
            av[i] = *(const float4*)(A + (size_t)grow * K + k0 + c4 * 4);
        }
        s16x8 bhv[BI], blv[BI];
        #pragma unroll
        for (int i = 0; i < BI; ++i) {
            int idx = tid + 256 * i;
            int col = idx >> 2, ch = idx & 3;
            bhv[i] = *(const s16x8*)(Bt_hi + (size_t)(bn + col) * K + k0 + ch * 8);
            blv[i] = *(const s16x8*)(Bt_lo + (size_t)(bn + col) * K + k0 + ch * 8);
        }
        __syncthreads();
        #pragma unroll
        for (int i = 0; i < 4; ++i) {
            int idx = tid + 256 * i;
            int row = idx >> 3, c4 = idx & 7;
            float vs[4] = {av[i].x, av[i].y, av[i].z, av[i].w};
            unsigned short h[4], l[4];
            #pragma unroll
            for (int j = 0; j < 4; ++j) {
                h[j] = f2bf(vs[j]);
                l[j] = f2bf(vs[j] - bf2f(h[j]));
            }
            *(s16x4*)&sAh[row][c4 * 4] = (s16x4){(short)h[0], (short)h[1], (short)h[2], (short)h[3]};
            *(s16x4*)&sAl[row][c4 * 4] = (s16x4){(short)l[0], (short)l[1], (short)l[2], (short)l[3]};
        }
        #pragma unroll
        for (int i = 0; i < BI; ++i) {
            int idx = tid + 256 * i;
            int col = idx >> 2, ch = idx & 3;
            *(s16x8*)&sBh[col][ch * 8] = bhv[i];
            *(s16x8*)&sBl[col][ch * 8] = blv[i];
        }
        __syncthreads();
        s16x8 afh[4], afl[4], bfh[CB], bfl[CB];
        #pragma unroll
        for (int rb = 0; rb < 4; ++rb) {
            int row = wr * 64 + rb * 16 + lr;
            afh[rb] = *(const s16x8*)&sAh[row][lk * 8];
            afl[rb] = *(const s16x8*)&sAl[row][lk * 8];
        }
        #pragma unroll
        for (int cb = 0; cb < CB; ++cb) {
            int col = wc * (BN / 2) + cb * 16 + lr;
            bfh[cb] = *(const s16x8*)&sBh[col][lk * 8];
            bfl[cb] = *(const s16x8*)&sBl[col][lk * 8];
        }
        #pragma unroll
        for (int rb = 0; rb < 4; ++rb)
            #pragma unroll
            for (int cb = 0; cb < CB; ++cb) {
                acc[rb][cb] = __builtin_amdgcn_mfma_f32_16x16x32_bf16(afh[rb], bfh[cb], acc[rb][cb], 0, 0, 0);
                acc[rb][cb] = __builtin_amdgcn_mfma_f32_16x16x32_bf16(afh[rb], bfl[cb], acc[rb][cb], 0, 0, 0);
                acc[rb][cb] = __builtin_amdgcn_mfma_f32_16x16x32_bf16(afl[rb], bfh[cb], acc[rb][cb], 0, 0, 0);
            }
    }
    // epilogue: C/D layout col=lane&15, row=(lane>>4)*4+r  [m89-verified]
    #pragma unroll
    for (int rb = 0; rb < 4; ++rb)
        #pragma unroll
        for (int cb = 0; cb < CB; ++cb)
            #pragma unroll
            for (int r = 0; r < 4; ++r) {
                int row = bm + wr * 64 + rb * 16 + lk * 4 + r;
                int col = bn + wc * (BN / 2) + cb * 16 + lr;
                if (row < M) Ch[(size_t)row * N + col] = (_Float16)acc[rb][cb][r];
            }
    // fused s/d epilogue
    {
        float af[CB], df[CB];
        #pragma unroll
        for (int cb = 0; cb < CB; ++cb) {
            int colg = bn + wc * (BN / 2) + cb * 16 + lr;
            af[cb] = asrc[colg];
            df[cb] = adst[colg];
        }
        #pragma unroll
        for (int rb = 0; rb < 4; ++rb)
            #pragma unroll
            for (int r = 0; r < 4; ++r) {
                float ps = 0.f, pd = 0.f;
                #pragma unroll
                for (int cb = 0; cb < CB; ++cb) {
                    ps += acc[rb][cb][r] * af[cb];
                    pd += acc[rb][cb][r] * df[cb];
                }
                #pragma unroll
                for (int m = 1; m < 16; m <<= 1) {
                    ps += __shfl_xor(ps, m);
                    pd += __shfl_xor(pd, m);
                }
                int row = bm + wr * 64 + rb * 16 + lk * 4 + r;
                if (lr == 0 && row < M) {
                    if constexpr (SD == 1) {
                        int head = (bn + wc * (BN / 2)) >> 6;
                        S[(size_t)row * (N >> 6) + head] = ps;
                        D[(size_t)row * (N >> 6) + head] = pd;
                    } else {
                        atomicAdd(&S[row], ps);
                        atomicAdd(&D[row], pd);
                    }
                }
            }
    }
}

// ---------------------------------------------------------------------------
__device__ __forceinline__ float leaky(float e) { return (e > 0.f) ? e : 0.2f * e; }

__device__ __forceinline__ float sel4(const float v[4], int idx) {
    float r = v[0];
    r = (idx == 1) ? v[1] : r;
    r = (idx == 2) ? v[2] : r;
    r = (idx == 3) ? v[3] : r;
    return r;
}

// GAT attention + aggregation, one wave per dst node, SINGLE fused pass:
// per 64-edge chunk: all lanes compute ex (1 edge/lane) -> per-wave LDS stash
// (no barrier; same-wave lgkmcnt ordering), then the 8-in-flight half8 MLP
// gather consumes ex/src from LDS. inv folded into epilogue (no ebuf).
template<int H>
__global__ __launch_bounds__(256)
void agg_k(const _Float16* __restrict__ hhalf,
           const float* __restrict__ s, const float* __restrict__ d,
           const float* __restrict__ bias, const int* __restrict__ rowptr,
           const int* __restrict__ csr_src, float* __restrict__ out, int n) {
    __shared__ float exs[4][H][64];
    __shared__ int   srcs[4][64];
    const int lane = threadIdx.x & 63;
    const int wv   = threadIdx.x >> 6;
    const int node = blockIdx.x * 4 + wv;
    if (node >= n) return;
    const int beg = rowptr[node], end = rowptr[node + 1];
    float dh[H], dn[H];
    #pragma unroll
    for (int h = 0; h < H; ++h) { dh[h] = d[node * H + h]; dn[h] = 0.f; }
    const half8* H8 = (const half8*)hhalf;

    if constexpr (H == 4) {
        const int sub = lane >> 5, c8 = lane & 31, head = c8 >> 3;
        float acc[8] = {};
        for (int c0 = beg; c0 < end; c0 += 64) {
            const int cend = (c0 + 64 < end) ? c0 + 64 : end;
            int e = c0 + lane;
            if (e < end) {
                int sidx = csr_src[e];
                float4 sv = *(const float4*)(s + (size_t)sidx * 4);
                float e0 = __expf(leaky(sv.x + dh[0]));
                float e1 = __expf(leaky(sv.y + dh[1]));
                float e2 = __expf(leaky(sv.z + dh[2]));
                float e3 = __expf(leaky(sv.w + dh[3]));
                srcs[wv][lane] = sidx;
                exs[wv][0][lane] = e0; exs[wv][1][lane] = e1;
                exs[wv][2][lane] = e2; exs[wv][3][lane] = e3;
                dn[0] += e0; dn[1] += e1; dn[2] += e2; dn[3] += e3;
            }
            asm volatile("s_waitcnt lgkmcnt(0)" ::: "memory");
            int i = c0;
            for (; i + 7 < cend; i += 8) {
                int j = i - c0 + sub;
                int s0 = srcs[wv][j],     s1 = srcs[wv][j + 2];
                int s2 = srcs[wv][j + 4], s3 = srcs[wv][j + 6];
                float x0 = exs[wv][head][j],     x1 = exs[wv][head][j + 2];
                float x2 = exs[wv][head][j + 4], x3 = exs[wv][head][j + 6];
                half8 h0 = H8[(size_t)s0 * 32 + c8];
                half8 h1 = H8[(size_t)s1 * 32 + c8];
                half8 h2 = H8[(size_t)s2 * 32 + c8];
                half8 h3 = H8[(size_t)s3 * 32 + c8];
                #pragma unroll
                for (int q = 0; q < 8; ++q)
                    acc[q] += x0 * (float)h0[q] + x1 * (float)h1[q]
                            + x2 * (float)h2[q] + x3 * (float)h3[q];
            }
            for (; i < cend; i += 2) {
                int e2i = i + sub;
                if (e2i < cend) {
                    int j = e2i - c0;
                    int s0 = srcs[wv][j];
                    float x = exs[wv][head][j];
                    half8 hh = H8[(size_t)s0 * 32 + c8];
                    #pragma unroll
                    for (int q = 0; q < 8; ++q) acc[q] += x * (float)hh[q];
                }
            }
        }
        float inv_[4];
        #pragma unroll
        for (int h = 0; h < 4; ++h) {
            #pragma unroll
            for (int m = 32; m; m >>= 1) dn[h] += __shfl_xor(dn[h], m);
            inv_[h] = 1.f / (dn[h] + 1e-16f);
        }
        const float invh = sel4(inv_, head);
        #pragma unroll
        for (int q = 0; q < 8; ++q) acc[q] += __shfl_xor(acc[q], 32);
        if (lane < 32) {
            float4 b0 = *(const float4*)(bias + c8 * 8);
            float4 b1 = *(const float4*)(bias + c8 * 8 + 4);
            float4 o0, o1;
            o0.x = fmaxf(acc[0] * invh + b0.x, 0.f);
            o0.y = fmaxf(acc[1] * invh + b0.y, 0.f);
            o0.z = fmaxf(acc[2] * invh + b0.z, 0.f);
            o0.w = fmaxf(acc[3] * invh + b0.w, 0.f);
            o1.x = fmaxf(acc[4] * invh + b1.x, 0.f);
            o1.y = fmaxf(acc[5] * invh + b1.y, 0.f);
            o1.z = fmaxf(acc[6] * invh + b1.z, 0.f);
            o1.w = fmaxf(acc[7] * invh + b1.w, 0.f);
            *(float4*)(out + (size_t)node * 256 + c8 * 8) = o0;
            *(float4*)(out + (size_t)node * 256 + c8 * 8 + 4) = o1;
        }
    } else {
        const int sub = lane >> 3, c8 = lane & 7;
        float acc[8] = {};
        for (int c0 = beg; c0 < end; c0 += 64) {
            const int cend = (c0 + 64 < end) ? c0 + 64 : end;
            int e = c0 + lane;
            if (e < end) {
                int sidx = csr_src[e];
                float ex = __expf(leaky(s[sidx] + dh[0]));
                srcs[wv][lane] = sidx;
                exs[wv][0][lane] = ex;
                dn[0] += ex;
            }
            asm volatile("s_waitcnt lgkmcnt(0)" ::: "memory");
            int i = c0;
            for (; i + 15 < cend; i += 16) {
                int j = i - c0 + sub;
                int s0 = srcs[wv][j], s1 = srcs[wv][j + 8];
                float x0 = exs[wv][0][j], x1 = exs[wv][0][j + 8];
                half8 h0 = H8[(size_t)s0 * 8 + c8];
                half8 h1 = H8[(size_t)s1 * 8 + c8];
                #pragma unroll
                for (int q = 0; q < 8; ++q)
                    acc[q] += x0 * (float)h0[q] + x1 * (float)h1[q];
            }
            for (; i < cend; i += 8) {
                int e2i = i + sub;
                if (e2i < cend) {
                    int j = e2i - c0;
                    int s0 = srcs[wv][j];
                    float x = exs[wv][0][j];
                    half8 hh = H8[(size_t)s0 * 8 + c8];
                    #pragma unroll
                    for (int q = 0; q < 8; ++q) acc[q] += x * (float)hh[q];
                }
            }
        }
        #pragma unroll
        for (int m = 32; m; m >>= 1) dn[0] += __shfl_xor(dn[0], m);
        const float inv0 = 1.f / (dn[0] + 1e-16f);
        #pragma unroll
        for (int m = 8; m <= 32; m <<= 1)
            #pragma unroll
            for (int q = 0; q < 8; ++q) acc[q] += __shfl_xor(acc[q], m);
        if (lane < 8) {
            float4 b0 = *(const float4*)(bias + c8 * 8);
            float4 b1 = *(const float4*)(bias + c8 * 8 + 4);
            float4 o0, o1;
            o0.x = fmaxf(acc[0] * inv0 + b0.x, 0.f);
            o0.y = fmaxf(acc[1] * inv0 + b0.y, 0.f);
            o0.z = fmaxf(acc[2] * inv0 + b0.z, 0.f);
            o0.w = fmaxf(acc[3] * inv0 + b0.w, 0.f);
            o1.x = fmaxf(acc[4] * inv0 + b1.x, 0.f);
            o1.y = fmaxf(acc[5] * inv0 + b1.y, 0.f);
            o1.z = fmaxf(acc[6] * inv0 + b1.z, 0.f);
            o1.w = fmaxf(acc[7] * inv0 + b1.w, 0.f);
            *(float4*)(out + (size_t)node * 64 + c8 * 8) = o0;
            *(float4*)(out + (size_t)node * 64 + c8 * 8 + 4) = o1;
        }
    }
}

// ---------------------------------------------------------------------------
// MFMA fused FF: out = softmax(relu(in@Wf1+bf1)@Wf2+bf2). 64-row blocks,
// 4 waves each owning 16 rows x all 64 cols. Weights split-bf16 transposed.
__global__ __launch_bounds__(256)
void ffm_k(const float* __restrict__ in,
           const unsigned short* __restrict__ w1h, const unsigned short* __restrict__ w1l,
           const float* __restrict__ bf1,
           const unsigned short* __restrict__ w2h, const unsigned short* __restrict__ w2l,
           const float* __restrict__ bf2, float* __restrict__ out, int M) {
    __shared__ unsigned short sAh[64][80], sAl[64][80];    // K chunks: [k/32]*40+(k%32)
    __shared__ unsigned short sW1h[64][80], sW1l[64][80];
    __shared__ unsigned short sW2h[64][80], sW2l[64][80];
    const int tid = threadIdx.x;
    const int bm = blockIdx.x * 64;
    const int w = tid >> 6, lane = tid & 63;
    const int lr = lane & 15, lk = lane >> 4;

    for (int c = tid; c < 512; c += 256) {
        int n = c >> 3, k8 = c & 7;
        int dcol = (k8 >> 2) * 40 + (k8 & 3) * 8;
        *(s16x8*)&sW1h[n][dcol] = *(const s16x8*)(w1h + n * 64 + k8 * 8);
        *(s16x8*)&sW1l[n][dcol] = *(const s16x8*)(w1l + n * 64 + k8 * 8);
        *(s16x8*)&sW2h[n][dcol] = *(const s16x8*)(w2h + n * 64 + k8 * 8);
        *(s16x8*)&sW2l[n][dcol] = *(const s16x8*)(w2l + n * 64 + k8 * 8);
    }
    #pragma unroll
    for (int i = 0; i < 4; ++i) {
        int c = tid + 256 * i;
        int row = c >> 4, c4 = c & 15;
        int grow = bm + row; if (grow >= M) grow = M - 1;
        float4 av = *(const float4*)(in + (size_t)grow * 64 + c4 * 4);
        float vs[4] = {av.x, av.y, av.z, av.w};
        unsigned short h[4], l[4];
        #pragma unroll
        for (int j = 0; j < 4; ++j) {
            h[j] = f2bf(vs[j]);
            l[j] = f2bf(vs[j] - bf2f(h[j]));
        }
        int dcol = (c4 >> 3) * 40 + (c4 & 7) * 4;
        *(s16x4*)&sAh[row][dcol] = (s16x4){(short)h[0], (short)h[1], (short)h[2], (short)h[3]};
        *(s16x4*)&sAl[row][dcol] = (s16x4){(short)l[0], (short)l[1], (short)l[2], (short)l[3]};
    }
    __syncthreads();
    f32x4 a1[4] = {};
    #pragma unroll
    for (int ks = 0; ks < 2; ++ks) {
        int koff = ks * 40 + lk * 8;
        s16x8 ah = *(const s16x8*)&sAh[w * 16 + lr][koff];
        s16x8 al = *(const s16x8*)&sAl[w * 16 + lr][koff];
        #pragma unroll
        for (int cb = 0; cb < 4; ++cb) {
            s16x8 bh = *(const s16x8*)&sW1h[cb * 16 + lr][koff];
            s16x8 bl = *(const s16x8*)&sW1l[cb * 16 + lr][koff];
            a1[cb] = __builtin_amdgcn_mfma_f32_16x16x32_bf16(ah, bh, a1[cb], 0, 0, 0);
            a1[cb] = __builtin_amdgcn_mfma_f32_16x16x32_bf16(ah, bl, a1[cb], 0, 0, 0);
            a1[cb] = __builtin_amdgcn_mfma_f32_16x16x32_bf16(al, bh, a1[cb], 0, 0, 0);
        }
    }
    __syncthreads();
    #pragma unroll
    for (int cb = 0; cb < 4; ++cb) {
        int col = cb * 16 + lr;
        float b = bf1[col];
        int dcol = (col >> 5) * 40 + (col & 31);
        #pragma unroll
        for (int r = 0; r < 4; ++r) {
            int row = w * 16 + lk * 4 + r;
            float y = fmaxf(a1[cb][r] + b, 0.f);
            unsigned short hh = f2bf(y);
            sAh[row][dcol] = hh;
            sAl[row][dcol] = f2bf(y - bf2f(hh));
        }
    }
    __syncthreads();
    f32x4 a2[4] = {};
    #pragma unroll
    for (int ks = 0; ks < 2; ++ks) {
        int koff = ks * 40 + lk * 8;
        s16x8 ah = *(const s16x8*)&sAh[w * 16 + lr][koff];
        s16x8 al = *(const s16x8*)&sAl[w * 16 + lr][koff];
        #pragma unroll
        for (int cb = 0; cb < 4; ++cb) {
            s16x8 bh = *(const s16x8*)&sW2h[cb * 16 + lr][koff];
            s16x8 bl = *(const s16x8*)&sW2l[cb * 16 + lr][koff];
            a2[cb] = __builtin_amdgcn_mfma_f32_16x16x32_bf16(ah, bh, a2[cb], 0, 0, 0);
            a2[cb] = __builtin_amdgcn_mfma_f32_16x16x32_bf16(ah, bl, a2[cb], 0, 0, 0);
            a2[cb] = __builtin_amdgcn_mfma_f32_16x16x32_bf16(al, bh, a2[cb], 0, 0, 0);
        }
    }
    float zb[4];
    #pragma unroll
    for (int cb = 0; cb < 4; ++cb) zb[cb] = bf2[cb * 16 + lr];
    #pragma unroll
    for (int r = 0; r < 4; ++r) {
        int row = bm + w * 16 + lk * 4 + r;
        float z0 = a2[0][r] + zb[0], z1 = a2[1][r] + zb[1];
        float z2 = a2[2][r] + zb[2], z3 = a2[3][r] + zb[3];
        float m = fmaxf(fmaxf(z0, z1), fmaxf(z2, z3));
        #pragma unroll
        for (int dd = 1; dd < 16; dd <<= 1) m = fmaxf(m, __shfl_xor(m, dd));
        float e0 = __expf(z0 - m), e1 = __expf(z1 - m);
        float e2 = __expf(z2 - m), e3 = __expf(z3 - m);
        float sum = e0 + e1 + e2 + e3;
        #pragma unroll
        for (int dd = 1; dd < 16; dd <<= 1) sum += __shfl_xor(sum, dd);
        float is = 1.f / sum;
        if (row < M) {
            out[(size_t)row * 64 + 0 + lr]  = e0 * is;
            out[(size_t)row * 64 + 16 + lr] = e1 * is;
            out[(size_t)row * 64 + 32 + lr] = e2 * is;
            out[(size_t)row * 64 + 48 + lr] = e3 * is;
        }
    }
}

// ---------------------------------------------------------------------------
extern "C" void kernel_launch(void* const* d_in, const int* in_sizes, int n_in,
                              void* d_out, int out_size, void* d_ws, size_t ws_size,
                              hipStream_t stream) {
    const float* x      = (const float*)d_in[0];
    const void*  ei     = d_in[1];
    const float* W1     = (const float*)d_in[2];
    const float* a_src1 = (const float*)d_in[3];
    const float* a_dst1 = (const float*)d_in[4];
    const float* b1     = (const float*)d_in[5];
    const float* W2     = (const float*)d_in[6];
    const float* a_src2 = (const float*)d_in[7];
    const float* a_dst2 = (const float*)d_in[8];
    const float* b2     = (const float*)d_in[9];
    const float* Wf1    = (const float*)d_in[10];
    const float* bf1    = (const float*)d_in[11];
    const float* Wf2    = (const float*)d_in[12];
    const float* bf2    = (const float*)d_in[13];
    float* outp = (float*)d_out;

    // workspace carve-up (256B aligned)
    char* ws = (char*)d_ws;
    size_t off = 0;
    auto take = [&](size_t bytes) -> char* {
        char* p = ws + off;
        off += (bytes + 255) & ~(size_t)255;
        return p;
    };
    int*   count  = (int*)take((size_t)NNODES * 4);
    int*   fill   = (int*)take((size_t)NNODES * 4);   // adjacent to count
    int*   rowptr = (int*)take((size_t)(NNODES + 1) * 4);
    int*   bsum   = (int*)take(64 * 4);
    int*   bpre   = (int*)take(64 * 4);
    int*   csr    = (int*)take((size_t)ETOT * 4);
    unsigned short* w1t_hi = (unsigned short*)take((size_t)256 * 256 * 2);
    unsigned short* w1t_lo = (unsigned short*)take((size_t)256 * 256 * 2);
    unsigned short* w2t_hi = (unsigned short*)take((size_t)64 * 256 * 2);
    unsigned short* w2t_lo = (unsigned short*)take((size_t)64 * 256 * 2);
    unsigned short* wf1t_hi = (unsigned short*)take((size_t)64 * 64 * 2);
    unsigned short* wf1t_lo = (unsigned short*)take((size_t)64 * 64 * 2);
    unsigned short* wf2t_hi = (unsigned short*)take((size_t)64 * 64 * 2);
    unsigned short* wf2t_lo = (unsigned short*)take((size_t)64 * 64 * 2);
    float* agg1   = (float*)take((size_t)NNODES * 256 * 4);
    float* s1     = (float*)take((size_t)NNODES * HEADS * 4);
    float* d1     = (float*)take((size_t)NNODES * HEADS * 4);  // adjacent to s1
    _Float16* h1h = (_Float16*)take((size_t)NNODES * 256 * 2);
    // layer-2 reuse: s2=s1, d2=d1, h2h=h1h, agg2=agg1
    float*    s2   = s1;
    float*    d2   = d1;
    float*    agg2 = agg1;
    _Float16* h2h  = h1h;

    // CSR build (shared by both GAT layers); edge width detected inline
    hipMemsetAsync(count, 0, (size_t)((char*)fill - (char*)count) + (size_t)NNODES * 4, stream);
    const int eblocks = (ETOT + 255) / 256;
    hist_k<<<eblocks, 256, 0, stream>>>(ei, count);
    const int sblocks = (NNODES + 1023) / 1024;  // 49
    scan1_k<<<sblocks, 1024, 0, stream>>>(count, rowptr, bsum, NNODES);
    scan2_k<<<1, 64, 0, stream>>>(bsum, bpre, sblocks, rowptr, NNODES);
    scan3_k<<<sblocks, 1024, 0, stream>>>(rowptr, bpre, NNODES);
    scatter_k<<<eblocks, 256, 0, stream>>>(ei, rowptr, fill, csr);

    // all weight pre-conversions in one launch
    convall_k<<<(90112 + 255) / 256, 256, 0, stream>>>(
        W1, W2, Wf1, Wf2, w1t_hi, w1t_lo, w2t_hi, w2t_lo,
        wf1t_hi, wf1t_lo, wf2t_hi, wf2t_lo);

    const int nodeblocks = NNODES / 4;  // 12500
    const int mblocks = (NNODES + 127) / 128;  // 391
    const dim3 gg1(2, mblocks);   // N=256, BN=128
    const dim3 gg2(1, mblocks);   // N=64,  BN=64

    // Layer 1: GEMM + fused s/d (direct store; each wave owns one head)
    gemm_mfma_k<128, 1><<<gg1, 256, 0, stream>>>(x, w1t_hi, w1t_lo,
        h1h, a_src1, a_dst1, s1, d1, NNODES, 256, 256);
    agg_k<HEADS><<<nodeblocks, 256, 0, stream>>>(h1h, s1, d1, b1,
        rowptr, csr, agg1, NNODES);

    // Layer 2: zero s2/d2 (single merged memset), GEMM + fused s/d (atomic)
    hipMemsetAsync(s2, 0, (size_t)((char*)d1 - (char*)s1) + (size_t)NNODES * 4, stream);
    gemm_mfma_k<64, 2><<<gg2, 256, 0, stream>>>(agg1, w2t_hi, w2t_lo,
        h2h, a_src2, a_dst2, s2, d2, NNODES, 64, 256);
    agg_k<1><<<nodeblocks, 256, 0, stream>>>(h2h, s2, d2, b2,
        rowptr, csr, agg2, NNODES);

    // FF + softmax via MFMA
    ffm_k<<<(NNODES + 63) / 64, 256, 0, stream>>>(agg2, wf1t_hi, wf1t_lo,
        bf1, wf2t_hi, wf2t_lo, bf2, outp, NNODES);
}

// Round 12
// 273.881 us; speedup vs baseline: 1.2961x; 1.0233x over previous
//
#include <hip/hip_runtime.h>

// Problem constants (from reference)
#define NNODES 50000
#define NEDGES 800000
#define INDIM  256
#define HIDC   64
#define HEADS  4
static constexpr int ETOT = NEDGES + NNODES;  // edges + self loops

typedef _Float16 half8 __attribute__((ext_vector_type(8)));
typedef short    s16x8 __attribute__((ext_vector_type(8)));   // 8 bf16 (4 VGPR) MFMA frag
typedef short    s16x4 __attribute__((ext_vector_type(4)));
typedef float    f32x4 __attribute__((ext_vector_type(4)));   // MFMA accumulator

// bf16 helpers (RNE)
__device__ __forceinline__ unsigned short f2bf(float f) {
    unsigned u = __float_as_uint(f);
    u += 0x7fffu + ((u >> 16) & 1u);
    return (unsigned short)(u >> 16);
}
__device__ __forceinline__ float bf2f(unsigned short h) {
    return __uint_as_float(((unsigned)h) << 16);
}

// ---------------------------------------------------------------------------
// inline edge-width detection: int64 => odd 32-bit words of first 32 pairs all
// zero (false-positive prob ~ (2e-5)^32 ~ 0). Uniform scalar loads, L2-hot.
__device__ __forceinline__ int is_int64(const unsigned* __restrict__ ei32) {
    int r = 1;
    #pragma unroll
    for (int i = 1; i < 64; i += 2) r &= (ei32[i] == 0u);
    return r;
}

__device__ __forceinline__ int load_idx(const void* ei, int is64, size_t pos) {
    return is64 ? (int)((const long long*)ei)[pos] : ((const int*)ei)[pos];
}

// ---------------------------------------------------------------------------
// CSR build: histogram of dst, two-level exclusive scan, scatter src ids
__global__ __launch_bounds__(256)
void hist_k(const void* __restrict__ ei, int* __restrict__ count) {
    int e = blockIdx.x * 256 + threadIdx.x;
    if (e >= ETOT) return;
    int is64 = is_int64((const unsigned*)ei);
    int dst = (e < NEDGES) ? load_idx(ei, is64, (size_t)NEDGES + e) : (e - NEDGES);
    atomicAdd(&count[dst], 1);
}

__global__ __launch_bounds__(1024)
void scan1_k(const int* __restrict__ count, int* __restrict__ rowptr,
             int* __restrict__ bsum, int n) {
    __shared__ int wsum[16];
    const int tid = threadIdx.x;
    const int lane = tid & 63;
    const int w = tid >> 6;
    int i = blockIdx.x * 1024 + tid;
    int v = (i < n) ? count[i] : 0;
    int x = v;
    #pragma unroll
    for (int dd = 1; dd < 64; dd <<= 1) {
        int y = __shfl_up(x, dd);
        if (lane >= dd) x += y;
    }
    if (lane == 63) wsum[w] = x;
    __syncthreads();
    int woff = 0, total = 0;
    #pragma unroll
    for (int j = 0; j < 16; ++j) {
        if (j < w) woff += wsum[j];
        total += wsum[j];
    }
    if (i < n) rowptr[i] = woff + x - v;
    if (tid == 0) bsum[blockIdx.x] = total;
}

// merged block-prefix + add: each block self-computes prefix over bsum[0..bid)
__global__ __launch_bounds__(1024)
void scan3_k(int* __restrict__ rowptr, const int* __restrict__ bsum,
             int nb, int n) {
    __shared__ int spre, stot;
    const int tid = threadIdx.x;
    if (tid < 64) {
        int vall = (tid < nb) ? bsum[tid] : 0;
        int vpre = (tid < (int)blockIdx.x) ? vall : 0;
        #pragma unroll
        for (int m = 32; m; m >>= 1) {
            vall += __shfl_xor(vall, m);
            vpre += __shfl_xor(vpre, m);
        }
        if (tid == 0) { spre = vpre; stot = vall; }
    }
    __syncthreads();
    int i = blockIdx.x * 1024 + tid;
    if (i < n) rowptr[i] += spre;
    if (blockIdx.x == 0 && tid == 0) rowptr[n] = stot;
}

__global__ __launch_bounds__(256)
void scatter_k(const void* __restrict__ ei, const int* __restrict__ rowptr,
               int* __restrict__ fill, int* __restrict__ csr_src) {
    int e = blockIdx.x * 256 + threadIdx.x;
    if (e >= ETOT) return;
    int is64 = is_int64((const unsigned*)ei);
    int src, dst;
    if (e < NEDGES) {
        src = load_idx(ei, is64, (size_t)e);
        dst = load_idx(ei, is64, (size_t)NEDGES + e);
    } else {
        src = e - NEDGES; dst = src;
    }
    int pos = rowptr[dst] + atomicAdd(&fill[dst], 1);
    csr_src[pos] = src;
}

// ---------------------------------------------------------------------------
// All-weights pre-convert in one launch: W[K][N] fp32 -> hi/lo bf16 [N][K]
__global__ __launch_bounds__(256)
void convall_k(const float* __restrict__ W1, const float* __restrict__ W2,
               const float* __restrict__ Wf1, const float* __restrict__ Wf2,
               unsigned short* __restrict__ w1h, unsigned short* __restrict__ w1l,
               unsigned short* __restrict__ w2h, unsigned short* __restrict__ w2l,
               unsigned short* __restrict__ f1h, unsigned short* __restrict__ f1l,
               unsigned short* __restrict__ f2h, unsigned short* __restrict__ f2l) {
    int idx = blockIdx.x * 256 + threadIdx.x;
    const float* W; unsigned short *th, *tl; int K, N;
    if (idx < 65536)       { W = W1;  th = w1h; tl = w1l; K = 256; N = 256; }
    else if (idx < 81920)  { idx -= 65536; W = W2;  th = w2h; tl = w2l; K = 256; N = 64; }
    else if (idx < 86016)  { idx -= 81920; W = Wf1; th = f1h; tl = f1l; K = 64;  N = 64; }
    else if (idx < 90112)  { idx -= 86016; W = Wf2; th = f2h; tl = f2l; K = 64;  N = 64; }
    else return;
    int k = idx / N, n = idx % N;
    float w = W[(size_t)k * N + n];
    unsigned short hi = f2bf(w);
    unsigned short lo = f2bf(w - bf2f(hi));
    th[(size_t)n * K + k] = hi;
    tl[(size_t)n * K + k] = lo;
}

// ---------------------------------------------------------------------------
// Split-bf16 MFMA GEMM: BM=128, BK=32, 4 waves 2x2. A is fp32 or fp16 (AT).
// Writes fp16 Ch + fused s/d dots. SD=1: direct store (wave owns a head's 64
// cols). SD=2: cross-wave LDS reduce then direct store (deterministic).
template<int BN, int SD, typename AT>
__global__ __launch_bounds__(256)
void gemm_mfma_k(const AT* __restrict__ A,
                 const unsigned short* __restrict__ Bt_hi,
                 const unsigned short* __restrict__ Bt_lo,
                 _Float16* __restrict__ Ch,
                 const float* __restrict__ asrc, const float* __restrict__ adst,
                 float* __restrict__ S, float* __restrict__ D,
                 int M, int N, int K) {
    constexpr int CB = BN / 32;          // 16-col frags per wave
    constexpr int BI = (BN * 4) / 256;   // B 16B-chunks per thread per half
    __shared__ unsigned short sAh[128][40], sAl[128][40];  // pad 40 (80B rows)
    __shared__ unsigned short sBh[BN][40], sBl[BN][40];
    const int tid = threadIdx.x;
    const int bm = blockIdx.y * 128;
    const int bn = blockIdx.x * BN;
    const int w = tid >> 6, lane = tid & 63;
    const int wr = w >> 1, wc = w & 1;
    const int lr = lane & 15, lk = lane >> 4;

    f32x4 acc[4][CB] = {};

    for (int k0 = 0; k0 < K; k0 += 32) {
        float4 av[4];
        half8 avh[2];
        if constexpr (sizeof(AT) == 4) {
            #pragma unroll
            for (int i = 0; i < 4; ++i) {
                int idx = tid + 256 * i;
                int row = idx >> 3, c4 = idx & 7;
                int grow = bm + row; if (grow >= M) grow = M - 1;
                av[i] = *(const float4*)((const float*)A + (size_t)grow * K + k0 + c4 * 4);
            }
        } else {
            #pragma unroll
            for (int i = 0; i < 2; ++i) {
                int idx = tid + 256 * i;
                int row = idx >> 2, c8 = idx & 3;
                int grow = bm + row; if (grow >= M) grow = M - 1;
                avh[i] = *(const half8*)((const _Float16*)A + (size_t)grow * K + k0 + c8 * 8);
            }
        }
        s16x8 bhv[BI], blv[BI];
        #pragma unroll
        for (int i = 0; i < BI; ++i) {
            int idx = tid + 256 * i;
            int col = idx >> 2, ch = idx & 3;
            bhv[i] = *(const s16x8*)(Bt_hi + (size_t)(bn + col) * K + k0 + ch * 8);
            blv[i] = *(const s16x8*)(Bt_lo + (size_t)(bn + col) * K + k0 + ch * 8);
        }
        __syncthreads();
        if constexpr (sizeof(AT) == 4) {
            #pragma unroll
            for (int i = 0; i < 4; ++i) {
                int idx = tid + 256 * i;
                int row = idx >> 3, c4 = idx & 7;
                float vs[4] = {av[i].x, av[i].y, av[i].z, av[i].w};
                unsigned short h[4], l[4];
                #pragma unroll
                for (int j = 0; j < 4; ++j) {
                    h[j] = f2bf(vs[j]);
                    l[j] = f2bf(vs[j] - bf2f(h[j]));
                }
                *(s16x4*)&sAh[row][c4 * 4] = (s16x4){(short)h[0], (short)h[1], (short)h[2], (short)h[3]};
                *(s16x4*)&sAl[row][c4 * 4] = (s16x4){(short)l[0], (short)l[1], (short)l[2], (short)l[3]};
            }
        } else {
            #pragma unroll
            for (int i = 0; i < 2; ++i) {
                int idx = tid + 256 * i;
                int row = idx >> 2, c8 = idx & 3;
                unsigned short h[8], l[8];
                #pragma unroll
                for (int j = 0; j < 8; ++j) {
                    float v = (float)avh[i][j];
                    h[j] = f2bf(v);
                    l[j] = f2bf(v - bf2f(h[j]));
                }
                *(s16x8*)&sAh[row][c8 * 8] = (s16x8){(short)h[0], (short)h[1], (short)h[2], (short)h[3],
                                                     (short)h[4], (short)h[5], (short)h[6], (short)h[7]};
                *(s16x8*)&sAl[row][c8 * 8] = (s16x8){(short)l[0], (short)l[1], (short)l[2], (short)l[3],
                                                     (short)l[4], (short)l[5], (short)l[6], (short)l[7]};
            }
        }
        #pragma unroll
        for (int i = 0; i < BI; ++i) {
            int idx = tid + 256 * i;
            int col = idx >> 2, ch = idx & 3;
            *(s16x8*)&sBh[col][ch * 8] = bhv[i];
            *(s16x8*)&sBl[col][ch * 8] = blv[i];
        }
        __syncthreads();
        s16x8 afh[4], afl[4], bfh[CB], bfl[CB];
        #pragma unroll
        for (int rb = 0; rb < 4; ++rb) {
            int row = wr * 64 + rb * 16 + lr;
            afh[rb] = *(const s16x8*)&sAh[row][lk * 8];
            afl[rb] = *(const s16x8*)&sAl[row][lk * 8];
        }
        #pragma unroll
        for (int cb = 0; cb < CB; ++cb) {
            int col = wc * (BN / 2) + cb * 16 + lr;
            bfh[cb] = *(const s16x8*)&sBh[col][lk * 8];
            bfl[cb] = *(const s16x8*)&sBl[col][lk * 8];
        }
        #pragma unroll
        for (int rb = 0; rb < 4; ++rb)
            #pragma unroll
            for (int cb = 0; cb < CB; ++cb) {
                acc[rb][cb] = __builtin_amdgcn_mfma_f32_16x16x32_bf16(afh[rb], bfh[cb], acc[rb][cb], 0, 0, 0);
                acc[rb][cb] = __builtin_amdgcn_mfma_f32_16x16x32_bf16(afh[rb], bfl[cb], acc[rb][cb], 0, 0, 0);
                acc[rb][cb] = __builtin_amdgcn_mfma_f32_16x16x32_bf16(afl[rb], bfh[cb], acc[rb][cb], 0, 0, 0);
            }
    }
    // epilogue: C/D layout col=lane&15, row=(lane>>4)*4+r  [m89-verified]
    #pragma unroll
    for (int rb = 0; rb < 4; ++rb)
        #pragma unroll
        for (int cb = 0; cb < CB; ++cb)
            #pragma unroll
            for (int r = 0; r < 4; ++r) {
                int row = bm + wr * 64 + rb * 16 + lk * 4 + r;
                int col = bn + wc * (BN / 2) + cb * 16 + lr;
                if (row < M) Ch[(size_t)row * N + col] = (_Float16)acc[rb][cb][r];
            }
    // fused s/d epilogue
    {
        float af[CB], df[CB];
        #pragma unroll
        for (int cb = 0; cb < CB; ++cb) {
            int colg = bn + wc * (BN / 2) + cb * 16 + lr;
            af[cb] = asrc[colg];
            df[cb] = adst[colg];
        }
        float psA[4][4], pdA[4][4];
        #pragma unroll
        for (int rb = 0; rb < 4; ++rb)
            #pragma unroll
            for (int r = 0; r < 4; ++r) {
                float ps = 0.f, pd = 0.f;
                #pragma unroll
                for (int cb = 0; cb < CB; ++cb) {
                    ps += acc[rb][cb][r] * af[cb];
                    pd += acc[rb][cb][r] * df[cb];
                }
                #pragma unroll
                for (int m = 1; m < 16; m <<= 1) {
                    ps += __shfl_xor(ps, m);
                    pd += __shfl_xor(pd, m);
                }
                psA[rb][r] = ps; pdA[rb][r] = pd;
            }
        if constexpr (SD == 1) {
            #pragma unroll
            for (int rb = 0; rb < 4; ++rb)
                #pragma unroll
                for (int r = 0; r < 4; ++r) {
                    int row = bm + wr * 64 + rb * 16 + lk * 4 + r;
                    if (lr == 0 && row < M) {
                        int head = (bn + wc * (BN / 2)) >> 6;
                        S[(size_t)row * (N >> 6) + head] = psA[rb][r];
                        D[(size_t)row * (N >> 6) + head] = pdA[rb][r];
                    }
                }
        } else {
            __shared__ float sps[128], spd[128];
            if (wc == 1 && lr == 0) {
                #pragma unroll
                for (int rb = 0; rb < 4; ++rb)
                    #pragma unroll
                    for (int r = 0; r < 4; ++r) {
                        int rowb = wr * 64 + rb * 16 + lk * 4 + r;
                        sps[rowb] = psA[rb][r]; spd[rowb] = pdA[rb][r];
                    }
            }
            __syncthreads();
            if (wc == 0 && lr == 0) {
                #pragma unroll
                for (int rb = 0; rb < 4; ++rb)
                    #pragma unroll
                    for (int r = 0; r < 4; ++r) {
                        int rowb = wr * 64 + rb * 16 + lk * 4 + r;
                        int row = bm + rowb;
                        if (row < M) {
                            S[row] = psA[rb][r] + sps[rowb];
                            D[row] = pdA[rb][r] + spd[rowb];
                        }
                    }
            }
        }
    }
}

// ---------------------------------------------------------------------------
__device__ __forceinline__ float leaky(float e) { return (e > 0.f) ? e : 0.2f * e; }

__device__ __forceinline__ float sel4(const float v[4], int idx) {
    float r = v[0];
    r = (idx == 1) ? v[1] : r;
    r = (idx == 2) ? v[2] : r;
    r = (idx == 3) ? v[3] : r;
    return r;
}

// GAT attention + aggregation, one wave per dst node, single fused pass
// (per-wave LDS stash for ex/src; 8-in-flight half8 MLP gather).
// H=4 writes fp16 output (feeds gemm2); H=1 writes fp32 (feeds ffm).
template<int H>
__global__ __launch_bounds__(256)
void agg_k(const _Float16* __restrict__ hhalf,
           const float* __restrict__ s, const float* __restrict__ d,
           const float* __restrict__ bias, const int* __restrict__ rowptr,
           const int* __restrict__ csr_src, _Float16* __restrict__ outh,
           float* __restrict__ outf, int n) {
    __shared__ float exs[4][H][64];
    __shared__ int   srcs[4][64];
    const int lane = threadIdx.x & 63;
    const int wv   = threadIdx.x >> 6;
    const int node = blockIdx.x * 4 + wv;
    if (node >= n) return;
    const int beg = rowptr[node], end = rowptr[node + 1];
    float dh[H], dn[H];
    #pragma unroll
    for (int h = 0; h < H; ++h) { dh[h] = d[node * H + h]; dn[h] = 0.f; }
    const half8* H8 = (const half8*)hhalf;

    if constexpr (H == 4) {
        const int sub = lane >> 5, c8 = lane & 31, head = c8 >> 3;
        float acc[8] = {};
        for (int c0 = beg; c0 < end; c0 += 64) {
            const int cend = (c0 + 64 < end) ? c0 + 64 : end;
            int e = c0 + lane;
            if (e < end) {
                int sidx = csr_src[e];
                float4 sv = *(const float4*)(s + (size_t)sidx * 4);
                float e0 = __expf(leaky(sv.x + dh[0]));
                float e1 = __expf(leaky(sv.y + dh[1]));
                float e2 = __expf(leaky(sv.z + dh[2]));
                float e3 = __expf(leaky(sv.w + dh[3]));
                srcs[wv][lane] = sidx;
                exs[wv][0][lane] = e0; exs[wv][1][lane] = e1;
                exs[wv][2][lane] = e2; exs[wv][3][lane] = e3;
                dn[0] += e0; dn[1] += e1; dn[2] += e2; dn[3] += e3;
            }
            asm volatile("s_waitcnt lgkmcnt(0)" ::: "memory");
            int i = c0;
            for (; i + 7 < cend; i += 8) {
                int j = i - c0 + sub;
                int s0 = srcs[wv][j],     s1 = srcs[wv][j + 2];
                int s2 = srcs[wv][j + 4], s3 = srcs[wv][j + 6];
                float x0 = exs[wv][head][j],     x1 = exs[wv][head][j + 2];
                float x2 = exs[wv][head][j + 4], x3 = exs[wv][head][j + 6];
                half8 h0 = H8[(size_t)s0 * 32 + c8];
                half8 h1 = H8[(size_t)s1 * 32 + c8];
                half8 h2 = H8[(size_t)s2 * 32 + c8];
                half8 h3 = H8[(size_t)s3 * 32 + c8];
                #pragma unroll
                for (int q = 0; q < 8; ++q)
                    acc[q] += x0 * (float)h0[q] + x1 * (float)h1[q]
                            + x2 * (float)h2[q] + x3 * (float)h3[q];
            }
            for (; i < cend; i += 2) {
                int e2i = i + sub;
                if (e2i < cend) {
                    int j = e2i - c0;
                    int s0 = srcs[wv][j];
                    float x = exs[wv][head][j];
                    half8 hh = H8[(size_t)s0 * 32 + c8];
                    #pragma unroll
                    for (int q = 0; q < 8; ++q) acc[q] += x * (float)hh[q];
                }
            }
        }
        float inv_[4];
        #pragma unroll
        for (int h = 0; h < 4; ++h) {
            #pragma unroll
            for (int m = 32; m; m >>= 1) dn[h] += __shfl_xor(dn[h], m);
            inv_[h] = 1.f / (dn[h] + 1e-16f);
        }
        const float invh = sel4(inv_, head);
        #pragma unroll
        for (int q = 0; q < 8; ++q) acc[q] += __shfl_xor(acc[q], 32);
        if (lane < 32) {
            float4 b0 = *(const float4*)(bias + c8 * 8);
            float4 b1 = *(const float4*)(bias + c8 * 8 + 4);
            float bb[8] = {b0.x, b0.y, b0.z, b0.w, b1.x, b1.y, b1.z, b1.w};
            half8 o;
            #pragma unroll
            for (int q = 0; q < 8; ++q)
                o[q] = (_Float16)fmaxf(acc[q] * invh + bb[q], 0.f);
            *(half8*)(outh + (size_t)node * 256 + c8 * 8) = o;
        }
    } else {
        const int sub = lane >> 3, c8 = lane & 7;
        float acc[8] = {};
        for (int c0 = beg; c0 < end; c0 += 64) {
            const int cend = (c0 + 64 < end) ? c0 + 64 : end;
            int e = c0 + lane;
            if (e < end) {
                int sidx = csr_src[e];
                float ex = __expf(leaky(s[sidx] + dh[0]));
                srcs[wv][lane] = sidx;
                exs[wv][0][lane] = ex;
                dn[0] += ex;
            }
            asm volatile("s_waitcnt lgkmcnt(0)" ::: "memory");
            int i = c0;
            for (; i + 15 < cend; i += 16) {
                int j = i - c0 + sub;
                int s0 = srcs[wv][j], s1 = srcs[wv][j + 8];
                float x0 = exs[wv][0][j], x1 = exs[wv][0][j + 8];
                half8 h0 = H8[(size_t)s0 * 8 + c8];
                half8 h1 = H8[(size_t)s1 * 8 + c8];
                #pragma unroll
                for (int q = 0; q < 8; ++q)
                    acc[q] += x0 * (float)h0[q] + x1 * (float)h1[q];
            }
            for (; i < cend; i += 8) {
                int e2i = i + sub;
                if (e2i < cend) {
                    int j = e2i - c0;
                    int s0 = srcs[wv][j];
                    float x = exs[wv][0][j];
                    half8 hh = H8[(size_t)s0 * 8 + c8];
                    #pragma unroll
                    for (int q = 0; q < 8; ++q) acc[q] += x * (float)hh[q];
                }
            }
        }
        #pragma unroll
        for (int m = 32; m; m >>= 1) dn[0] += __shfl_xor(dn[0], m);
        const float inv0 = 1.f / (dn[0] + 1e-16f);
        #pragma unroll
        for (int m = 8; m <= 32; m <<= 1)
            #pragma unroll
            for (int q = 0; q < 8; ++q) acc[q] += __shfl_xor(acc[q], m);
        if (lane < 8) {
            float4 b0 = *(const float4*)(bias + c8 * 8);
            float4 b1 = *(const float4*)(bias + c8 * 8 + 4);
            float4 o0, o1;
            o0.x = fmaxf(acc[0] * inv0 + b0.x, 0.f);
            o0.y = fmaxf(acc[1] * inv0 + b0.y, 0.f);
            o0.z = fmaxf(acc[2] * inv0 + b0.z, 0.f);
            o0.w = fmaxf(acc[3] * inv0 + b0.w, 0.f);
            o1.x = fmaxf(acc[4] * inv0 + b1.x, 0.f);
            o1.y = fmaxf(acc[5] * inv0 + b1.y, 0.f);
            o1.z = fmaxf(acc[6] * inv0 + b1.z, 0.f);
            o1.w = fmaxf(acc[7] * inv0 + b1.w, 0.f);
            *(float4*)(outf + (size_t)node * 64 + c8 * 8) = o0;
            *(float4*)(outf + (size_t)node * 64 + c8 * 8 + 4) = o1;
        }
    }
}

// ---------------------------------------------------------------------------
// MFMA fused FF: out = softmax(relu(in@Wf1+bf1)@Wf2+bf2). 64-row blocks,
// 4 waves each owning 16 rows x all 64 cols. Weights split-bf16 transposed.
__global__ __launch_bounds__(256)
void ffm_k(const float* __restrict__ in,
           const unsigned short* __restrict__ w1h, const unsigned short* __restrict__ w1l,
           const float* __restrict__ bf1,
           const unsigned short* __restrict__ w2h, const unsigned short* __restrict__ w2l,
           const float* __restrict__ bf2, float* __restrict__ out, int M) {
    __shared__ unsigned short sAh[64][80], sAl[64][80];    // K chunks: [k/32]*40+(k%32)
    __shared__ unsigned short sW1h[64][80], sW1l[64][80];
    __shared__ unsigned short sW2h[64][80], sW2l[64][80];
    const int tid = threadIdx.x;
    const int bm = blockIdx.x * 64;
    const int w = tid >> 6, lane = tid & 63;
    const int lr = lane & 15, lk = lane >> 4;

    for (int c = tid; c < 512; c += 256) {
        int n = c >> 3, k8 = c & 7;
        int dcol = (k8 >> 2) * 40 + (k8 & 3) * 8;
        *(s16x8*)&sW1h[n][dcol] = *(const s16x8*)(w1h + n * 64 + k8 * 8);
        *(s16x8*)&sW1l[n][dcol] = *(const s16x8*)(w1l + n * 64 + k8 * 8);
        *(s16x8*)&sW2h[n][dcol] = *(const s16x8*)(w2h + n * 64 + k8 * 8);
        *(s16x8*)&sW2l[n][dcol] = *(const s16x8*)(w2l + n * 64 + k8 * 8);
    }
    #pragma unroll
    for (int i = 0; i < 4; ++i) {
        int c = tid + 256 * i;
        int row = c >> 4, c4 = c & 15;
        int grow = bm + row; if (grow >= M) grow = M - 1;
        float4 av = *(const float4*)(in + (size_t)grow * 64 + c4 * 4);
        float vs[4] = {av.x, av.y, av.z, av.w};
        unsigned short h[4], l[4];
        #pragma unroll
        for (int j = 0; j < 4; ++j) {
            h[j] = f2bf(vs[j]);
            l[j] = f2bf(vs[j] - bf2f(h[j]));
        }
        int dcol = (c4 >> 3) * 40 + (c4 & 7) * 4;
        *(s16x4*)&sAh[row][dcol] = (s16x4){(short)h[0], (short)h[1], (short)h[2], (short)h[3]};
        *(s16x4*)&sAl[row][dcol] = (s16x4){(short)l[0], (short)l[1], (short)l[2], (short)l[3]};
    }
    __syncthreads();
    f32x4 a1[4] = {};
    #pragma unroll
    for (int ks = 0; ks < 2; ++ks) {
        int koff = ks * 40 + lk * 8;
        s16x8 ah = *(const s16x8*)&sAh[w * 16 + lr][koff];
        s16x8 al = *(const s16x8*)&sAl[w * 16 + lr][koff];
        #pragma unroll
        for (int cb = 0; cb < 4; ++cb) {
            s16x8 bh = *(const s16x8*)&sW1h[cb * 16 + lr][koff];
            s16x8 bl = *(const s16x8*)&sW1l[cb * 16 + lr][koff];
            a1[cb] = __builtin_amdgcn_mfma_f32_16x16x32_bf16(ah, bh, a1[cb], 0, 0, 0);
            a1[cb] = __builtin_amdgcn_mfma_f32_16x16x32_bf16(ah, bl, a1[cb], 0, 0, 0);
            a1[cb] = __builtin_amdgcn_mfma_f32_16x16x32_bf16(al, bh, a1[cb], 0, 0, 0);
        }
    }
    __syncthreads();
    #pragma unroll
    for (int cb = 0; cb < 4; ++cb) {
        int col = cb * 16 + lr;
        float b = bf1[col];
        int dcol = (col >> 5) * 40 + (col & 31);
        #pragma unroll
        for (int r = 0; r < 4; ++r) {
            int row = w * 16 + lk * 4 + r;
            float y = fmaxf(a1[cb][r] + b, 0.f);
            unsigned short hh = f2bf(y);
            sAh[row][dcol] = hh;
            sAl[row][dcol] = f2bf(y - bf2f(hh));
        }
    }
    __syncthreads();
    f32x4 a2[4] = {};
    #pragma unroll
    for (int ks = 0; ks < 2; ++ks) {
        int koff = ks * 40 + lk * 8;
        s16x8 ah = *(const s16x8*)&sAh[w * 16 + lr][koff];
        s16x8 al = *(const s16x8*)&sAl[w * 16 + lr][koff];
        #pragma unroll
        for (int cb = 0; cb < 4; ++cb) {
            s16x8 bh = *(const s16x8*)&sW2h[cb * 16 + lr][koff];
            s16x8 bl = *(const s16x8*)&sW2l[cb * 16 + lr][koff];
            a2[cb] = __builtin_amdgcn_mfma_f32_16x16x32_bf16(ah, bh, a2[cb], 0, 0, 0);
            a2[cb] = __builtin_amdgcn_mfma_f32_16x16x32_bf16(ah, bl, a2[cb], 0, 0, 0);
            a2[cb] = __builtin_amdgcn_mfma_f32_16x16x32_bf16(al, bh, a2[cb], 0, 0, 0);
        }
    }
    float zb[4];
    #pragma unroll
    for (int cb = 0; cb < 4; ++cb) zb[cb] = bf2[cb * 16 + lr];
    #pragma unroll
    for (int r = 0; r < 4; ++r) {
        int row = bm + w * 16 + lk * 4 + r;
        float z0 = a2[0][r] + zb[0], z1 = a2[1][r] + zb[1];
        float z2 = a2[2][r] + zb[2], z3 = a2[3][r] + zb[3];
        float m = fmaxf(fmaxf(z0, z1), fmaxf(z2, z3));
        #pragma unroll
        for (int dd = 1; dd < 16; dd <<= 1) m = fmaxf(m, __shfl_xor(m, dd));
        float e0 = __expf(z0 - m), e1 = __expf(z1 - m);
        float e2 = __expf(z2 - m), e3 = __expf(z3 - m);
        float sum = e0 + e1 + e2 + e3;
        #pragma unroll
        for (int dd = 1; dd < 16; dd <<= 1) sum += __shfl_xor(sum, dd);
        float is = 1.f / sum;
        if (row < M) {
            out[(size_t)row * 64 + 0 + lr]  = e0 * is;
            out[(size_t)row * 64 + 16 + lr] = e1 * is;
            out[(size_t)row * 64 + 32 + lr] = e2 * is;
            out[(size_t)row * 64 + 48 + lr] = e3 * is;
        }
    }
}

// ---------------------------------------------------------------------------
extern "C" void kernel_launch(void* const* d_in, const int* in_sizes, int n_in,
                              void* d_out, int out_size, void* d_ws, size_t ws_size,
                              hipStream_t stream) {
    const float* x      = (const float*)d_in[0];
    const void*  ei     = d_in[1];
    const float* W1     = (const float*)d_in[2];
    const float* a_src1 = (const float*)d_in[3];
    const float* a_dst1 = (const float*)d_in[4];
    const float* b1     = (const float*)d_in[5];
    const float* W2     = (const float*)d_in[6];
    const float* a_src2 = (const float*)d_in[7];
    const float* a_dst2 = (const float*)d_in[8];
    const float* b2     = (const float*)d_in[9];
    const float* Wf1    = (const float*)d_in[10];
    const float* bf1    = (const float*)d_in[11];
    const float* Wf2    = (const float*)d_in[12];
    const float* bf2    = (const float*)d_in[13];
    float* outp = (float*)d_out;

    // workspace carve-up (256B aligned)
    char* ws = (char*)d_ws;
    size_t off = 0;
    auto take = [&](size_t bytes) -> char* {
        char* p = ws + off;
        off += (bytes + 255) & ~(size_t)255;
        return p;
    };
    int*   count  = (int*)take((size_t)NNODES * 4);
    int*   fill   = (int*)take((size_t)NNODES * 4);   // adjacent to count
    int*   rowptr = (int*)take((size_t)(NNODES + 1) * 4);
    int*   bsum   = (int*)take(64 * 4);
    int*   csr    = (int*)take((size_t)ETOT * 4);
    unsigned short* w1t_hi = (unsigned short*)take((size_t)256 * 256 * 2);
    unsigned short* w1t_lo = (unsigned short*)take((size_t)256 * 256 * 2);
    unsigned short* w2t_hi = (unsigned short*)take((size_t)64 * 256 * 2);
    unsigned short* w2t_lo = (unsigned short*)take((size_t)64 * 256 * 2);
    unsigned short* wf1t_hi = (unsigned short*)take((size_t)64 * 64 * 2);
    unsigned short* wf1t_lo = (unsigned short*)take((size_t)64 * 64 * 2);
    unsigned short* wf2t_hi = (unsigned short*)take((size_t)64 * 64 * 2);
    unsigned short* wf2t_lo = (unsigned short*)take((size_t)64 * 64 * 2);
    float* agg2   = (float*)take((size_t)NNODES * 64 * 4);
    float* s1     = (float*)take((size_t)NNODES * HEADS * 4);
    float* d1     = (float*)take((size_t)NNODES * HEADS * 4);
    _Float16* h1h   = (_Float16*)take((size_t)NNODES * 256 * 2);
    _Float16* agg1h = (_Float16*)take((size_t)NNODES * 256 * 2);
    // layer-2 reuse: s2=s1, d2=d1, h2h=h1h (dead after agg4)
    float*    s2  = s1;
    float*    d2  = d1;
    _Float16* h2h = h1h;

    // CSR build (shared by both GAT layers); edge width detected inline
    hipMemsetAsync(count, 0, (size_t)((char*)fill - (char*)count) + (size_t)NNODES * 4, stream);
    const int eblocks = (ETOT + 255) / 256;
    hist_k<<<eblocks, 256, 0, stream>>>(ei, count);
    const int sblocks = (NNODES + 1023) / 1024;  // 49
    scan1_k<<<sblocks, 1024, 0, stream>>>(count, rowptr, bsum, NNODES);
    scan3_k<<<sblocks, 1024, 0, stream>>>(rowptr, bsum, sblocks, NNODES);
    scatter_k<<<eblocks, 256, 0, stream>>>(ei, rowptr, fill, csr);

    // all weight pre-conversions in one launch
    convall_k<<<(90112 + 255) / 256, 256, 0, stream>>>(
        W1, W2, Wf1, Wf2, w1t_hi, w1t_lo, w2t_hi, w2t_lo,
        wf1t_hi, wf1t_lo, wf2t_hi, wf2t_lo);

    const int nodeblocks = NNODES / 4;  // 12500
    const int mblocks = (NNODES + 127) / 128;  // 391
    const dim3 gg1(2, mblocks);   // N=256, BN=128
    const dim3 gg2(1, mblocks);   // N=64,  BN=64

    // Layer 1: GEMM + fused s/d (direct store; each wave owns one head)
    gemm_mfma_k<128, 1, float><<<gg1, 256, 0, stream>>>(x, w1t_hi, w1t_lo,
        h1h, a_src1, a_dst1, s1, d1, NNODES, 256, 256);
    agg_k<HEADS><<<nodeblocks, 256, 0, stream>>>(h1h, s1, d1, b1,
        rowptr, csr, agg1h, nullptr, NNODES);

    // Layer 2: GEMM (fp16 A) + fused s/d (LDS cross-wave reduce, no memset)
    gemm_mfma_k<64, 2, _Float16><<<gg2, 256, 0, stream>>>(agg1h, w2t_hi, w2t_lo,
        h2h, a_src2, a_dst2, s2, d2, NNODES, 64, 256);
    agg_k<1><<<nodeblocks, 256, 0, stream>>>(h2h, s2, d2, b2,
        rowptr, csr, nullptr, agg2, NNODES);

    // FF + softmax via MFMA
    ffm_k<<<(NNODES + 63) / 64, 256, 0, stream>>>(agg2, wf1t_hi, wf1t_lo,
        bf1, wf2t_hi, wf2t_lo, bf2, outp, NNODES);
}